// Round 2
// baseline (16183.662 us; speedup 1.0000x reference)
//
#include <hip/hip_runtime.h>

constexpr int cB  = 4;
constexpr int cN  = 1024;
constexpr int cD  = 768;
constexpr int cH  = 12;
constexpr int cHD = 64;
constexpr int cHID = 3072;
constexpr int cBN = cB * cN;   // 4096 rows

// ---------------------------------------------------------------------------
// LayerNorm: one block (256 thr) per row of D=768 (3 elems/thread)
// ---------------------------------------------------------------------------
__global__ __launch_bounds__(256)
void ln_kernel(const float* __restrict__ x, const float* __restrict__ g,
               const float* __restrict__ b, float* __restrict__ y) {
    int row = blockIdx.x;
    int t   = threadIdx.x;
    const float* xr = x + (size_t)row * cD;
    float v0 = xr[t], v1 = xr[t + 256], v2 = xr[t + 512];

    __shared__ float red[256];
    red[t] = v0 + v1 + v2;
    __syncthreads();
    #pragma unroll
    for (int o = 128; o > 0; o >>= 1) { if (t < o) red[t] += red[t + o]; __syncthreads(); }
    float mean = red[0] / (float)cD;
    __syncthreads();

    float d0 = v0 - mean, d1 = v1 - mean, d2 = v2 - mean;
    red[t] = d0 * d0 + d1 * d1 + d2 * d2;
    __syncthreads();
    #pragma unroll
    for (int o = 128; o > 0; o >>= 1) { if (t < o) red[t] += red[t + o]; __syncthreads(); }
    float rstd = rsqrtf(red[0] / (float)cD + 1e-5f);

    float* yr = y + (size_t)row * cD;
    yr[t]       = d0 * rstd * g[t]       + b[t];
    yr[t + 256] = d1 * rstd * g[t + 256] + b[t + 256];
    yr[t + 512] = d2 * rstd * g[t + 512] + b[t + 512];
}

// ---------------------------------------------------------------------------
// Tiled GEMM: C[M,Nn] = act(A[M,K] @ W[K,Nn] + bias) (+ res)
// 64x64 tile / block of 256 thr, 4x4 micro-tile, TK=16, fp32 accumulate.
// act: 0 = none, 1 = exact GELU. res nullable (added after activation).
// ---------------------------------------------------------------------------
__global__ __launch_bounds__(256)
void gemm_kernel(const float* __restrict__ A, const float* __restrict__ W,
                 const float* __restrict__ bias, const float* __restrict__ res,
                 float* __restrict__ C, int M, int K, int Nn, int act) {
    constexpr int TM = 64, TN = 64, TK = 16;
    __shared__ float As[TM][TK + 1];
    __shared__ float Ws[TK][TN + 1];

    int tx = threadIdx.x & 15;
    int ty = threadIdx.x >> 4;
    int bm = blockIdx.x * TM;
    int bn = blockIdx.y * TN;

    float acc[4][4] = {{0.f}};

    for (int k0 = 0; k0 < K; k0 += TK) {
        #pragma unroll
        for (int i = 0; i < 4; i++) {
            int idx = threadIdx.x + i * 256;
            int r = idx >> 4, c = idx & 15;
            As[r][c] = A[(size_t)(bm + r) * K + k0 + c];
        }
        #pragma unroll
        for (int i = 0; i < 4; i++) {
            int idx = threadIdx.x + i * 256;
            int r = idx >> 6, c = idx & 63;
            Ws[r][c] = W[(size_t)(k0 + r) * Nn + bn + c];
        }
        __syncthreads();
        #pragma unroll
        for (int kk = 0; kk < TK; kk++) {
            float av[4], wv[4];
            #pragma unroll
            for (int i = 0; i < 4; i++) av[i] = As[ty * 4 + i][kk];
            #pragma unroll
            for (int j = 0; j < 4; j++) wv[j] = Ws[kk][tx * 4 + j];
            #pragma unroll
            for (int i = 0; i < 4; i++)
                #pragma unroll
                for (int j = 0; j < 4; j++)
                    acc[i][j] = fmaf(av[i], wv[j], acc[i][j]);
        }
        __syncthreads();
    }

    #pragma unroll
    for (int i = 0; i < 4; i++) {
        int m = bm + ty * 4 + i;
        #pragma unroll
        for (int j = 0; j < 4; j++) {
            int n = bn + tx * 4 + j;
            float c = acc[i][j] + bias[n];
            if (act == 1) c = 0.5f * c * (1.0f + erff(c * 0.70710678118f));
            if (res) c += res[(size_t)m * Nn + n];
            C[(size_t)m * Nn + n] = c;
        }
    }
}

// ---------------------------------------------------------------------------
// Attention: one block (256 thr) per (b, h, q-row). scores->LDS, softmax,
// chunked AV. scale carries the sign (cross-attn negates scores).
// strides in elements (3*D for packed QKV, D for separate buffers).
// ---------------------------------------------------------------------------
__global__ __launch_bounds__(256)
void attn_kernel(const float* __restrict__ Qp, const float* __restrict__ Kp,
                 const float* __restrict__ Vp, float* __restrict__ O,
                 int q_stride, int kv_stride, float scale) {
    __shared__ float qs[cHD];
    __shared__ float sc[cN];
    __shared__ float red[256];
    __shared__ float part[4][cHD];

    int blk = blockIdx.x;
    int qi  = blk & (cN - 1);
    int bh  = blk >> 10;
    int h   = bh % cH;
    int bb  = bh / cH;
    int t   = threadIdx.x;

    const float* qrow = Qp + (size_t)(bb * cN + qi) * q_stride + h * cHD;
    if (t < cHD) qs[t] = qrow[t];
    __syncthreads();

    // scores: each thread computes 4 of the 1024 scores
    float lmax = -1e30f;
    #pragma unroll
    for (int jj = 0; jj < 4; jj++) {
        int j = t + jj * 256;
        const float* krow = Kp + (size_t)(bb * cN + j) * kv_stride + h * cHD;
        const float4* kr = reinterpret_cast<const float4*>(krow);
        float s = 0.f;
        #pragma unroll
        for (int q4 = 0; q4 < 16; q4++) {
            float4 kv4 = kr[q4];
            s = fmaf(qs[q4 * 4 + 0], kv4.x, s);
            s = fmaf(qs[q4 * 4 + 1], kv4.y, s);
            s = fmaf(qs[q4 * 4 + 2], kv4.z, s);
            s = fmaf(qs[q4 * 4 + 3], kv4.w, s);
        }
        s *= scale;
        sc[j] = s;
        lmax = fmaxf(lmax, s);
    }
    red[t] = lmax;
    __syncthreads();
    #pragma unroll
    for (int o = 128; o > 0; o >>= 1) { if (t < o) red[t] = fmaxf(red[t], red[t + o]); __syncthreads(); }
    float mx = red[0];
    __syncthreads();

    float lsum = 0.f;
    #pragma unroll
    for (int jj = 0; jj < 4; jj++) {
        int j = t + jj * 256;
        float e = __expf(sc[j] - mx);
        sc[j] = e;
        lsum += e;
    }
    red[t] = lsum;
    __syncthreads();
    #pragma unroll
    for (int o = 128; o > 0; o >>= 1) { if (t < o) red[t] += red[t + o]; __syncthreads(); }
    float inv = 1.0f / red[0];
    __syncthreads();

    // AV: chunk c handles k in [c*256, c*256+256), lane dim d = t&63
    int cch = t >> 6, dd = t & 63;
    float acc = 0.f;
    for (int j = cch * 256; j < cch * 256 + 256; j++) {
        const float* vrow = Vp + (size_t)(bb * cN + j) * kv_stride + h * cHD;
        acc = fmaf(sc[j], vrow[dd], acc);
    }
    part[cch][dd] = acc;
    __syncthreads();
    if (t < cHD) {
        float o4 = (part[0][t] + part[1][t] + part[2][t] + part[3][t]) * inv;
        O[(size_t)(bb * cN + qi) * cD + h * cHD + t] = o4;
    }
}

// ---------------------------------------------------------------------------
extern "C" void kernel_launch(void* const* d_in, const int* in_sizes, int n_in,
                              void* d_out, int out_size, void* d_ws, size_t ws_size,
                              hipStream_t stream) {
    const float* img_tok  = (const float*)d_in[0];
    const float* evt_tok  = (const float*)d_in[1];
    const float* ln_q1_g  = (const float*)d_in[2];
    const float* ln_q1_b  = (const float*)d_in[3];
    const float* ln_kv1_g = (const float*)d_in[4];
    const float* ln_kv1_b = (const float*)d_in[5];
    const float* ln_q2_g  = (const float*)d_in[6];
    const float* ln_q2_b  = (const float*)d_in[7];
    const float* ln_kv2_g = (const float*)d_in[8];
    const float* ln_kv2_b = (const float*)d_in[9];
    const float* ln_mi_g  = (const float*)d_in[10];
    const float* ln_mi_b  = (const float*)d_in[11];
    const float* ln_me_g  = (const float*)d_in[12];
    const float* ln_me_b  = (const float*)d_in[13];
    const float* si_qkv_w  = (const float*)d_in[14];
    const float* si_qkv_b  = (const float*)d_in[15];
    const float* si_proj_w = (const float*)d_in[16];
    const float* si_proj_b = (const float*)d_in[17];
    const float* se_qkv_w  = (const float*)d_in[18];
    const float* se_qkv_b  = (const float*)d_in[19];
    const float* se_proj_w = (const float*)d_in[20];
    const float* se_proj_b = (const float*)d_in[21];
    const float* xei_q_w = (const float*)d_in[22];
    const float* xei_q_b = (const float*)d_in[23];
    const float* xei_k_w = (const float*)d_in[24];
    const float* xei_k_b = (const float*)d_in[25];
    const float* xei_v_w = (const float*)d_in[26];
    const float* xei_v_b = (const float*)d_in[27];
    const float* xei_p_w = (const float*)d_in[28];
    const float* xei_p_b = (const float*)d_in[29];
    const float* xie_q_w = (const float*)d_in[30];
    const float* xie_q_b = (const float*)d_in[31];
    const float* xie_k_w = (const float*)d_in[32];
    const float* xie_k_b = (const float*)d_in[33];
    const float* xie_v_w = (const float*)d_in[34];
    const float* xie_v_b = (const float*)d_in[35];
    const float* xie_p_w = (const float*)d_in[36];
    const float* xie_p_b = (const float*)d_in[37];
    const float* mi_fc1_w = (const float*)d_in[38];
    const float* mi_fc1_b = (const float*)d_in[39];
    const float* mi_fc2_w = (const float*)d_in[40];
    const float* mi_fc2_b = (const float*)d_in[41];
    const float* me_fc1_w = (const float*)d_in[42];
    const float* me_fc1_b = (const float*)d_in[43];
    const float* me_fc2_w = (const float*)d_in[44];
    const float* me_fc2_b = (const float*)d_in[45];

    const size_t U = (size_t)cBN * cD;       // 3,145,728 elems
    float* ws = (float*)d_ws;
    float* T1 = ws;                          // [0,U)   (QKV spans T1..T3, Hb spans T1..T4)
    float* T2 = ws + U;
    float* T3 = ws + 2 * U;
    float* T4 = ws + 3 * U;
    float* T5 = ws + 4 * U;                  // LN scratch
    float* out_img = (float*)d_out;
    float* out_evt = out_img + U;

    const dim3 thr(256);
    const dim3 lnGrid(cBN);
    const dim3 attnGrid(cB * cH * cN);
    const float SC = 0.125f;                 // 1/sqrt(64)

    auto gemm = [&](const float* A_, const float* W_, const float* b_, const float* r_,
                    float* C_, int M_, int K_, int N_, int act_) {
        dim3 g(M_ / 64, N_ / 64);
        hipLaunchKernelGGL(gemm_kernel, g, thr, 0, stream, A_, W_, b_, r_, C_, M_, K_, N_, act_);
    };
    auto ln = [&](const float* x_, const float* g_, const float* b_, float* y_) {
        hipLaunchKernelGGL(ln_kernel, lnGrid, thr, 0, stream, x_, g_, b_, y_);
    };
    auto attn = [&](const float* q_, const float* k_, const float* v_, float* o_,
                    int qs_, int kvs_, float sc_) {
        hipLaunchKernelGGL(attn_kernel, attnGrid, thr, 0, stream, q_, k_, v_, o_, qs_, kvs_, sc_);
    };

    // ---- self-attn img: i1 = img_tok + proj(attn(ln_q1(img_tok)))
    ln(img_tok, ln_q1_g, ln_q1_b, T5);
    gemm(T5, si_qkv_w, si_qkv_b, nullptr, T1, cBN, cD, 3 * cD, 0);   // packed QKV -> T1..T3
    attn(T1, T1 + cD, T1 + 2 * cD, T4, 3 * cD, 3 * cD, SC);
    gemm(T4, si_proj_w, si_proj_b, img_tok, out_img, cBN, cD, cD, 0);

    // ---- self-attn evt: e1 = evt_tok + proj(attn(ln_kv1(evt_tok)))
    ln(evt_tok, ln_kv1_g, ln_kv1_b, T5);
    gemm(T5, se_qkv_w, se_qkv_b, nullptr, T1, cBN, cD, 3 * cD, 0);
    attn(T1, T1 + cD, T1 + 2 * cD, T4, 3 * cD, 3 * cD, SC);
    gemm(T4, se_proj_w, se_proj_b, evt_tok, out_evt, cBN, cD, cD, 0);

    // ---- cross-attn img (xei): q=ln_q2(i1), kv=ln_kv2(e1), NEGATED scores
    ln(out_img, ln_q2_g, ln_q2_b, T5);
    gemm(T5, xei_q_w, xei_q_b, nullptr, T1, cBN, cD, cD, 0);         // Q_xei
    ln(out_evt, ln_kv2_g, ln_kv2_b, T5);
    gemm(T5, xei_k_w, xei_k_b, nullptr, T2, cBN, cD, cD, 0);         // K_xei
    gemm(T5, xei_v_w, xei_v_b, nullptr, T3, cBN, cD, cD, 0);         // V_xei
    attn(T1, T2, T3, T4, cD, cD, -SC);                               // O_xei -> T4

    // xie projections while i1 (out_img) and e1 (out_evt) are still intact
    ln(out_img, ln_kv2_g, ln_kv2_b, T5);
    gemm(T5, xie_k_w, xie_k_b, nullptr, T1, cBN, cD, cD, 0);         // K_xie
    gemm(T5, xie_v_w, xie_v_b, nullptr, T2, cBN, cD, cD, 0);         // V_xie
    ln(out_evt, ln_q2_g, ln_q2_b, T5);
    gemm(T5, xie_q_w, xie_q_b, nullptr, T3, cBN, cD, cD, 0);         // Q_xie

    // now safe to overwrite i1
    gemm(T4, xei_p_w, xei_p_b, out_img, out_img, cBN, cD, cD, 0);    // i2
    attn(T3, T1, T2, T4, cD, cD, -SC);                               // O_xie -> T4
    gemm(T4, xie_p_w, xie_p_b, out_evt, out_evt, cBN, cD, cD, 0);    // e2

    // ---- MLP img
    ln(out_img, ln_mi_g, ln_mi_b, T5);
    gemm(T5, mi_fc1_w, mi_fc1_b, nullptr, T1, cBN, cD, cHID, 1);     // GELU, T1..T4
    gemm(T1, mi_fc2_w, mi_fc2_b, out_img, out_img, cBN, cHID, cD, 0);

    // ---- MLP evt
    ln(out_evt, ln_me_g, ln_me_b, T5);
    gemm(T5, me_fc1_w, me_fc1_b, nullptr, T1, cBN, cD, cHID, 1);
    gemm(T1, me_fc2_w, me_fc2_b, out_evt, out_evt, cBN, cHID, cD, 0);
}

// Round 3
// 4166.721 us; speedup vs baseline: 3.8840x; 3.8840x over previous
//
#include <hip/hip_runtime.h>

constexpr int cB  = 4;
constexpr int cN  = 1024;
constexpr int cD  = 768;
constexpr int cH  = 12;
constexpr int cHD = 64;
constexpr int cHID = 3072;
constexpr int cBN = cB * cN;   // 4096 rows

// ---------------------------------------------------------------------------
// LayerNorm: one block (256 thr) per row of D=768 (3 elems/thread)
// ---------------------------------------------------------------------------
__global__ __launch_bounds__(256)
void ln_kernel(const float* __restrict__ x, const float* __restrict__ g,
               const float* __restrict__ b, float* __restrict__ y) {
    int row = blockIdx.x;
    int t   = threadIdx.x;
    const float* xr = x + (size_t)row * cD;
    float v0 = xr[t], v1 = xr[t + 256], v2 = xr[t + 512];

    __shared__ float red[256];
    red[t] = v0 + v1 + v2;
    __syncthreads();
    #pragma unroll
    for (int o = 128; o > 0; o >>= 1) { if (t < o) red[t] += red[t + o]; __syncthreads(); }
    float mean = red[0] / (float)cD;
    __syncthreads();

    float d0 = v0 - mean, d1 = v1 - mean, d2 = v2 - mean;
    red[t] = d0 * d0 + d1 * d1 + d2 * d2;
    __syncthreads();
    #pragma unroll
    for (int o = 128; o > 0; o >>= 1) { if (t < o) red[t] += red[t + o]; __syncthreads(); }
    float rstd = rsqrtf(red[0] / (float)cD + 1e-5f);

    float* yr = y + (size_t)row * cD;
    yr[t]       = d0 * rstd * g[t]       + b[t];
    yr[t + 256] = d1 * rstd * g[t + 256] + b[t + 256];
    yr[t + 512] = d2 * rstd * g[t + 512] + b[t + 512];
}

// ---------------------------------------------------------------------------
// Tiled GEMM: C[M,Nn] = act(A[M,K] @ W[K,Nn] + bias) (+ res)
// 64x64 tile / block of 256 thr, 4x4 micro-tile, TK=16, fp32 accumulate.
// ---------------------------------------------------------------------------
__global__ __launch_bounds__(256)
void gemm_kernel(const float* __restrict__ A, const float* __restrict__ W,
                 const float* __restrict__ bias, const float* __restrict__ res,
                 float* __restrict__ C, int M, int K, int Nn, int act) {
    constexpr int TM = 64, TN = 64, TK = 16;
    __shared__ float As[TM][TK + 1];
    __shared__ float Ws[TK][TN + 1];

    int tx = threadIdx.x & 15;
    int ty = threadIdx.x >> 4;
    int bm = blockIdx.x * TM;
    int bn = blockIdx.y * TN;

    float acc[4][4] = {{0.f}};

    for (int k0 = 0; k0 < K; k0 += TK) {
        #pragma unroll
        for (int i = 0; i < 4; i++) {
            int idx = threadIdx.x + i * 256;
            int r = idx >> 4, c = idx & 15;
            As[r][c] = A[(size_t)(bm + r) * K + k0 + c];
        }
        #pragma unroll
        for (int i = 0; i < 4; i++) {
            int idx = threadIdx.x + i * 256;
            int r = idx >> 6, c = idx & 63;
            Ws[r][c] = W[(size_t)(k0 + r) * Nn + bn + c];
        }
        __syncthreads();
        #pragma unroll
        for (int kk = 0; kk < TK; kk++) {
            float av[4], wv[4];
            #pragma unroll
            for (int i = 0; i < 4; i++) av[i] = As[ty * 4 + i][kk];
            #pragma unroll
            for (int j = 0; j < 4; j++) wv[j] = Ws[kk][tx * 4 + j];
            #pragma unroll
            for (int i = 0; i < 4; i++)
                #pragma unroll
                for (int j = 0; j < 4; j++)
                    acc[i][j] = fmaf(av[i], wv[j], acc[i][j]);
        }
        __syncthreads();
    }

    #pragma unroll
    for (int i = 0; i < 4; i++) {
        int m = bm + ty * 4 + i;
        #pragma unroll
        for (int j = 0; j < 4; j++) {
            int n = bn + tx * 4 + j;
            float c = acc[i][j] + bias[n];
            if (act == 1) c = 0.5f * c * (1.0f + erff(c * 0.70710678118f));
            if (res) c += res[(size_t)m * Nn + n];
            C[(size_t)m * Nn + n] = c;
        }
    }
}

// ---------------------------------------------------------------------------
// Flash attention: one block (256 thr) per (b, h, 64-row Q tile).
// K/V tiles staged in LDS (64x reuse), online softmax, O in registers.
// Q & K stored TRANSPOSED in LDS -> contiguous float4 reads in score loop.
// scale carries the sign (cross-attn negates scores) and is folded into Q.
// ---------------------------------------------------------------------------
constexpr int QT = 64, KT = 64;

__global__ __launch_bounds__(256)
void fattn_kernel(const float* __restrict__ Qp, const float* __restrict__ Kp,
                  const float* __restrict__ Vp, float* __restrict__ O,
                  int q_stride, int kv_stride, float scale) {
    __shared__ float Qt[cHD][QT + 4];     // transposed, pre-scaled: Qt[d][r]
    __shared__ float KV[KT][cHD + 4];     // K transposed KV[d][c] / V row KV[c][d]
    __shared__ float Ps[QT][KT + 1];
    __shared__ float pred[QT][17];        // partial row max / row sum
    __shared__ float mrow[QT], lrow[QT], arow[QT];

    int t  = threadIdx.x;
    int tx = t & 15, ty = t >> 4;
    int blk = blockIdx.x;
    int qt0 = (blk & 15) * QT;            // cN/QT = 16
    int bh  = blk >> 4;
    int h   = bh % cH;
    int bb  = bh / cH;

    int lr = t >> 2, lq = t & 3;          // loader: row in tile, quarter of dims

    // Q tile: load, scale, transpose into LDS
    {
        const float4* q4 = (const float4*)(Qp + (size_t)(bb * cN + qt0 + lr) * q_stride
                                           + h * cHD + lq * 16);
        #pragma unroll
        for (int f = 0; f < 4; f++) {
            float4 v = q4[f];
            int d = lq * 16 + f * 4;
            Qt[d + 0][lr] = v.x * scale;
            Qt[d + 1][lr] = v.y * scale;
            Qt[d + 2][lr] = v.z * scale;
            Qt[d + 3][lr] = v.w * scale;
        }
    }
    if (t < QT) { mrow[t] = -1e30f; lrow[t] = 0.f; }
    float o[4][4] = {{0.f, 0.f, 0.f, 0.f}};
    __syncthreads();

    for (int kt0 = 0; kt0 < cN; kt0 += KT) {
        // ---- K tile: load transposed
        {
            const float4* k4 = (const float4*)(Kp + (size_t)(bb * cN + kt0 + lr) * kv_stride
                                               + h * cHD + lq * 16);
            #pragma unroll
            for (int f = 0; f < 4; f++) {
                float4 v = k4[f];
                int d = lq * 16 + f * 4;
                KV[d + 0][lr] = v.x;  KV[d + 1][lr] = v.y;
                KV[d + 2][lr] = v.z;  KV[d + 3][lr] = v.w;
            }
        }
        __syncthreads();

        // ---- S = (scale*Q) K^T : acc[i][j] = S[ty*4+i][tx*4+j]
        float acc[4][4] = {{0.f}};
        #pragma unroll 4
        for (int d = 0; d < cHD; d++) {
            float4 a4 = *(const float4*)&Qt[d][ty * 4];
            float4 b4 = *(const float4*)&KV[d][tx * 4];
            float av[4] = {a4.x, a4.y, a4.z, a4.w};
            float bv[4] = {b4.x, b4.y, b4.z, b4.w};
            #pragma unroll
            for (int i = 0; i < 4; i++)
                #pragma unroll
                for (int j = 0; j < 4; j++)
                    acc[i][j] = fmaf(av[i], bv[j], acc[i][j]);
        }

        // ---- partial row max
        #pragma unroll
        for (int i = 0; i < 4; i++)
            pred[ty * 4 + i][tx] = fmaxf(fmaxf(acc[i][0], acc[i][1]),
                                         fmaxf(acc[i][2], acc[i][3]));
        __syncthreads();

        if (t < QT) {
            float tm = -1e30f;
            #pragma unroll
            for (int k = 0; k < 16; k++) tm = fmaxf(tm, pred[t][k]);
            float mo = mrow[t];
            float mn = fmaxf(mo, tm);
            mrow[t] = mn;
            arow[t] = __expf(mo - mn);
        }
        __syncthreads();

        // ---- P = exp(S - m), partial row sums, rescale O; V tile load (KV free)
        #pragma unroll
        for (int i = 0; i < 4; i++) {
            int row = ty * 4 + i;
            float mn = mrow[row];
            float al = arow[row];
            float ps = 0.f;
            #pragma unroll
            for (int j = 0; j < 4; j++) {
                float p = __expf(acc[i][j] - mn);
                Ps[row][tx * 4 + j] = p;
                ps += p;
                o[i][j] *= al;
            }
            pred[row][tx] = ps;
        }
        {
            const float4* v4 = (const float4*)(Vp + (size_t)(bb * cN + kt0 + lr) * kv_stride
                                               + h * cHD + lq * 16);
            #pragma unroll
            for (int f = 0; f < 4; f++)
                *(float4*)&KV[lr][lq * 16 + f * 4] = v4[f];
        }
        __syncthreads();

        // ---- l update + O += P V
        if (t < QT) {
            float s = 0.f;
            #pragma unroll
            for (int k = 0; k < 16; k++) s += pred[t][k];
            lrow[t] = lrow[t] * arow[t] + s;
        }
        #pragma unroll 4
        for (int c = 0; c < KT; c++) {
            float4 b4 = *(const float4*)&KV[c][tx * 4];
            #pragma unroll
            for (int i = 0; i < 4; i++) {
                float a = Ps[ty * 4 + i][c];
                o[i][0] = fmaf(a, b4.x, o[i][0]);
                o[i][1] = fmaf(a, b4.y, o[i][1]);
                o[i][2] = fmaf(a, b4.z, o[i][2]);
                o[i][3] = fmaf(a, b4.w, o[i][3]);
            }
        }
        __syncthreads();
    }

    // ---- epilogue: O / l
    #pragma unroll
    for (int i = 0; i < 4; i++) {
        int row = ty * 4 + i;
        float inv = 1.0f / lrow[row];
        float4 v = make_float4(o[i][0] * inv, o[i][1] * inv, o[i][2] * inv, o[i][3] * inv);
        *(float4*)(O + (size_t)(bb * cN + qt0 + row) * cD + h * cHD + tx * 4) = v;
    }
}

// ---------------------------------------------------------------------------
extern "C" void kernel_launch(void* const* d_in, const int* in_sizes, int n_in,
                              void* d_out, int out_size, void* d_ws, size_t ws_size,
                              hipStream_t stream) {
    const float* img_tok  = (const float*)d_in[0];
    const float* evt_tok  = (const float*)d_in[1];
    const float* ln_q1_g  = (const float*)d_in[2];
    const float* ln_q1_b  = (const float*)d_in[3];
    const float* ln_kv1_g = (const float*)d_in[4];
    const float* ln_kv1_b = (const float*)d_in[5];
    const float* ln_q2_g  = (const float*)d_in[6];
    const float* ln_q2_b  = (const float*)d_in[7];
    const float* ln_kv2_g = (const float*)d_in[8];
    const float* ln_kv2_b = (const float*)d_in[9];
    const float* ln_mi_g  = (const float*)d_in[10];
    const float* ln_mi_b  = (const float*)d_in[11];
    const float* ln_me_g  = (const float*)d_in[12];
    const float* ln_me_b  = (const float*)d_in[13];
    const float* si_qkv_w  = (const float*)d_in[14];
    const float* si_qkv_b  = (const float*)d_in[15];
    const float* si_proj_w = (const float*)d_in[16];
    const float* si_proj_b = (const float*)d_in[17];
    const float* se_qkv_w  = (const float*)d_in[18];
    const float* se_qkv_b  = (const float*)d_in[19];
    const float* se_proj_w = (const float*)d_in[20];
    const float* se_proj_b = (const float*)d_in[21];
    const float* xei_q_w = (const float*)d_in[22];
    const float* xei_q_b = (const float*)d_in[23];
    const float* xei_k_w = (const float*)d_in[24];
    const float* xei_k_b = (const float*)d_in[25];
    const float* xei_v_w = (const float*)d_in[26];
    const float* xei_v_b = (const float*)d_in[27];
    const float* xei_p_w = (const float*)d_in[28];
    const float* xei_p_b = (const float*)d_in[29];
    const float* xie_q_w = (const float*)d_in[30];
    const float* xie_q_b = (const float*)d_in[31];
    const float* xie_k_w = (const float*)d_in[32];
    const float* xie_k_b = (const float*)d_in[33];
    const float* xie_v_w = (const float*)d_in[34];
    const float* xie_v_b = (const float*)d_in[35];
    const float* xie_p_w = (const float*)d_in[36];
    const float* xie_p_b = (const float*)d_in[37];
    const float* mi_fc1_w = (const float*)d_in[38];
    const float* mi_fc1_b = (const float*)d_in[39];
    const float* mi_fc2_w = (const float*)d_in[40];
    const float* mi_fc2_b = (const float*)d_in[41];
    const float* me_fc1_w = (const float*)d_in[42];
    const float* me_fc1_b = (const float*)d_in[43];
    const float* me_fc2_w = (const float*)d_in[44];
    const float* me_fc2_b = (const float*)d_in[45];

    const size_t U = (size_t)cBN * cD;       // 3,145,728 elems
    float* ws = (float*)d_ws;
    float* T1 = ws;
    float* T2 = ws + U;
    float* T3 = ws + 2 * U;
    float* T4 = ws + 3 * U;
    float* T5 = ws + 4 * U;                  // LN scratch
    float* out_img = (float*)d_out;
    float* out_evt = out_img + U;

    const dim3 thr(256);
    const dim3 lnGrid(cBN);
    const dim3 attnGrid(cB * cH * (cN / QT));   // 768
    const float SC = 0.125f;                 // 1/sqrt(64)

    auto gemm = [&](const float* A_, const float* W_, const float* b_, const float* r_,
                    float* C_, int M_, int K_, int N_, int act_) {
        dim3 g(M_ / 64, N_ / 64);
        hipLaunchKernelGGL(gemm_kernel, g, thr, 0, stream, A_, W_, b_, r_, C_, M_, K_, N_, act_);
    };
    auto ln = [&](const float* x_, const float* g_, const float* b_, float* y_) {
        hipLaunchKernelGGL(ln_kernel, lnGrid, thr, 0, stream, x_, g_, b_, y_);
    };
    auto attn = [&](const float* q_, const float* k_, const float* v_, float* o_,
                    int qs_, int kvs_, float sc_) {
        hipLaunchKernelGGL(fattn_kernel, attnGrid, thr, 0, stream, q_, k_, v_, o_, qs_, kvs_, sc_);
    };

    // ---- self-attn img: i1 = img_tok + proj(attn(ln_q1(img_tok)))
    ln(img_tok, ln_q1_g, ln_q1_b, T5);
    gemm(T5, si_qkv_w, si_qkv_b, nullptr, T1, cBN, cD, 3 * cD, 0);   // packed QKV -> T1..T3
    attn(T1, T1 + cD, T1 + 2 * cD, T4, 3 * cD, 3 * cD, SC);
    gemm(T4, si_proj_w, si_proj_b, img_tok, out_img, cBN, cD, cD, 0);

    // ---- self-attn evt: e1 = evt_tok + proj(attn(ln_kv1(evt_tok)))
    ln(evt_tok, ln_kv1_g, ln_kv1_b, T5);
    gemm(T5, se_qkv_w, se_qkv_b, nullptr, T1, cBN, cD, 3 * cD, 0);
    attn(T1, T1 + cD, T1 + 2 * cD, T4, 3 * cD, 3 * cD, SC);
    gemm(T4, se_proj_w, se_proj_b, evt_tok, out_evt, cBN, cD, cD, 0);

    // ---- cross-attn img (xei): q=ln_q2(i1), kv=ln_kv2(e1), NEGATED scores
    ln(out_img, ln_q2_g, ln_q2_b, T5);
    gemm(T5, xei_q_w, xei_q_b, nullptr, T1, cBN, cD, cD, 0);         // Q_xei
    ln(out_evt, ln_kv2_g, ln_kv2_b, T5);
    gemm(T5, xei_k_w, xei_k_b, nullptr, T2, cBN, cD, cD, 0);         // K_xei
    gemm(T5, xei_v_w, xei_v_b, nullptr, T3, cBN, cD, cD, 0);         // V_xei
    attn(T1, T2, T3, T4, cD, cD, -SC);                               // O_xei -> T4

    // xie projections while i1 (out_img) and e1 (out_evt) are still intact
    ln(out_img, ln_kv2_g, ln_kv2_b, T5);
    gemm(T5, xie_k_w, xie_k_b, nullptr, T1, cBN, cD, cD, 0);         // K_xie
    gemm(T5, xie_v_w, xie_v_b, nullptr, T2, cBN, cD, cD, 0);         // V_xie
    ln(out_evt, ln_q2_g, ln_q2_b, T5);
    gemm(T5, xie_q_w, xie_q_b, nullptr, T3, cBN, cD, cD, 0);         // Q_xie

    // now safe to overwrite i1
    gemm(T4, xei_p_w, xei_p_b, out_img, out_img, cBN, cD, cD, 0);    // i2
    attn(T3, T1, T2, T4, cD, cD, -SC);                               // O_xie -> T4
    gemm(T4, xie_p_w, xie_p_b, out_evt, out_evt, cBN, cD, cD, 0);    // e2

    // ---- MLP img
    ln(out_img, ln_mi_g, ln_mi_b, T5);
    gemm(T5, mi_fc1_w, mi_fc1_b, nullptr, T1, cBN, cD, cHID, 1);     // GELU, T1..T4
    gemm(T1, mi_fc2_w, mi_fc2_b, out_img, out_img, cBN, cHID, cD, 0);

    // ---- MLP evt
    ln(out_evt, ln_me_g, ln_me_b, T5);
    gemm(T5, me_fc1_w, me_fc1_b, nullptr, T1, cBN, cD, cHID, 1);
    gemm(T1, me_fc2_w, me_fc2_b, out_evt, out_evt, cBN, cHID, cD, 0);
}

// Round 4
// 1637.811 us; speedup vs baseline: 9.8813x; 2.5441x over previous
//
#include <hip/hip_runtime.h>

constexpr int cB  = 4;
constexpr int cN  = 1024;
constexpr int cD  = 768;
constexpr int cH  = 12;
constexpr int cHD = 64;
constexpr int cHID = 3072;
constexpr int cBN = cB * cN;   // 4096 rows

typedef __attribute__((ext_vector_type(8))) short bf16x8;
typedef __attribute__((ext_vector_type(4))) float f32x4;

static __device__ __forceinline__ unsigned short f2bf(float f) {
    union { float f; unsigned int u; } v; v.f = f;
    unsigned int u = v.u;
    return (unsigned short)((u + 0x7FFFu + ((u >> 16) & 1u)) >> 16);
}
static __device__ __forceinline__ float lo2f(unsigned int u) { return __uint_as_float(u << 16); }
static __device__ __forceinline__ float hi2f(unsigned int u) { return __uint_as_float(u & 0xffff0000u); }

static __device__ __forceinline__ void gl_lds16(const void* g, void* l) {
    __builtin_amdgcn_global_load_lds(
        (const __attribute__((address_space(1))) unsigned int*)g,
        (__attribute__((address_space(3))) unsigned int*)l, 16, 0, 0);
}

// ---------------------------------------------------------------------------
// Weight convert: W fp32 [K][N] row-major -> bf16 B-swizzled:
//   elem(n,k) at ((n>>4)*(K/8)+(k>>3))*128 + (n&15)*8 + (k&7)
// block: 64k x 64n tile, 256 thr.
// ---------------------------------------------------------------------------
__global__ __launch_bounds__(256)
void wconv_kernel(const float* __restrict__ W, unsigned short* __restrict__ Wo,
                  int K, int N) {
    __shared__ float Ls[64][68];
    int k0 = blockIdx.x * 64, n0 = blockIdx.y * 64;
    int t = threadIdx.x;
    int lr = t >> 4, lc = (t & 15) * 4;
    #pragma unroll
    for (int i = 0; i < 4; i++) {
        float4 v = *(const float4*)&W[(size_t)(k0 + lr + i * 16) * N + n0 + lc];
        Ls[lr + i * 16][lc + 0] = v.x;  Ls[lr + i * 16][lc + 1] = v.y;
        Ls[lr + i * 16][lc + 2] = v.z;  Ls[lr + i * 16][lc + 3] = v.w;
    }
    __syncthreads();
    int mt = t >> 3;                 // 0..31 micro-tiles (4 nblk x 8 kblk)
    int nb = mt & 3, kb = mt >> 2;
    int sub = t & 7;                 // handles n-rows sub*2, sub*2+1
    int K8 = K >> 3;
    size_t chunk = ((size_t)(n0 / 16 + nb) * K8 + (size_t)(k0 / 8 + kb)) * 128;
    unsigned short buf[16];
    #pragma unroll
    for (int rr = 0; rr < 2; rr++) {
        int n_r = sub * 2 + rr;
        #pragma unroll
        for (int kk = 0; kk < 8; kk++)
            buf[rr * 8 + kk] = f2bf(Ls[kb * 8 + kk][nb * 16 + n_r]);
    }
    uint4 w0, w1;
    w0.x = buf[0] | ((unsigned)buf[1] << 16);   w0.y = buf[2] | ((unsigned)buf[3] << 16);
    w0.z = buf[4] | ((unsigned)buf[5] << 16);   w0.w = buf[6] | ((unsigned)buf[7] << 16);
    w1.x = buf[8] | ((unsigned)buf[9] << 16);   w1.y = buf[10] | ((unsigned)buf[11] << 16);
    w1.z = buf[12] | ((unsigned)buf[13] << 16); w1.w = buf[14] | ((unsigned)buf[15] << 16);
    *(uint4*)&Wo[chunk + sub * 16]     = w0;
    *(uint4*)&Wo[chunk + sub * 16 + 8] = w1;
}

// ---------------------------------------------------------------------------
// LayerNorm: fp32 in -> bf16 A-swizzled out. Block = 16 rows, 256 thr.
//   elem(m,k) at ((m>>4)*96 + (k>>3))*128 + (m&15)*8 + (k&7)   [K=768]
// ---------------------------------------------------------------------------
__global__ __launch_bounds__(256)
void ln_kernel(const float* __restrict__ x, const float* __restrict__ g,
               const float* __restrict__ b, unsigned short* __restrict__ y) {
    __shared__ float psum[16][17], psq[16][17];
    __shared__ float mean_s[16], rstd_s[16];
    int R = blockIdx.x;
    int t = threadIdx.x;
    int r = t >> 4, c16 = t & 15;
    const float* xr = x + ((size_t)R * 16 + r) * cD;
    float s = 0.f, sq = 0.f;
    #pragma unroll
    for (int i = 0; i < 12; i++) {
        float4 v = *(const float4*)&xr[c16 * 4 + i * 64];
        s  += v.x + v.y + v.z + v.w;
        sq += v.x * v.x + v.y * v.y + v.z * v.z + v.w * v.w;
    }
    psum[r][c16] = s; psq[r][c16] = sq;
    __syncthreads();
    if (t < 16) {
        float ss = 0.f, qq = 0.f;
        #pragma unroll
        for (int i = 0; i < 16; i++) { ss += psum[t][i]; qq += psq[t][i]; }
        float m = ss / (float)cD;
        mean_s[t] = m;
        rstd_s[t] = rsqrtf(qq / (float)cD - m * m + 1e-5f);
    }
    __syncthreads();
    int r2 = t & 15, cslot = t >> 4;
    const float* xr2 = x + ((size_t)R * 16 + r2) * cD;
    float m = mean_s[r2], rs = rstd_s[r2];
    for (int c = cslot; c < 96; c += 16) {
        float4 a0 = *(const float4*)&xr2[c * 8];
        float4 a1 = *(const float4*)&xr2[c * 8 + 4];
        float4 g0 = *(const float4*)&g[c * 8];
        float4 g1 = *(const float4*)&g[c * 8 + 4];
        float4 b0 = *(const float4*)&b[c * 8];
        float4 b1 = *(const float4*)&b[c * 8 + 4];
        unsigned short o[8];
        o[0] = f2bf((a0.x - m) * rs * g0.x + b0.x);
        o[1] = f2bf((a0.y - m) * rs * g0.y + b0.y);
        o[2] = f2bf((a0.z - m) * rs * g0.z + b0.z);
        o[3] = f2bf((a0.w - m) * rs * g0.w + b0.w);
        o[4] = f2bf((a1.x - m) * rs * g1.x + b1.x);
        o[5] = f2bf((a1.y - m) * rs * g1.y + b1.y);
        o[6] = f2bf((a1.z - m) * rs * g1.z + b1.z);
        o[7] = f2bf((a1.w - m) * rs * g1.w + b1.w);
        uint4 w;
        w.x = o[0] | ((unsigned)o[1] << 16); w.y = o[2] | ((unsigned)o[3] << 16);
        w.z = o[4] | ((unsigned)o[5] << 16); w.w = o[6] | ((unsigned)o[7] << 16);
        *(uint4*)&y[((size_t)R * 96 + c) * 128 + r2 * 8] = w;
    }
}

// ---------------------------------------------------------------------------
// MFMA GEMM: C = act(A@W + bias)(+res). A bf16 A-swizzled [M][K]; W bf16
// B-swizzled [K][N]. 64x64 tile per single-wave block; 16x16x32 MFMA.
// mode 0: bf16 row-major. mode 1: bf16 A-swizzled + GELU. mode 2: fp32 + res.
// ---------------------------------------------------------------------------
__global__ __launch_bounds__(64)
void mfma_gemm(const unsigned short* __restrict__ A,
               const unsigned short* __restrict__ Bw,
               const float* __restrict__ bias, const float* __restrict__ res,
               void* __restrict__ Cout, int M, int K, int N, int mode) {
    __shared__ bf16x8 aF[4 * 64];
    __shared__ bf16x8 bF[4 * 64];
    int l = threadIdx.x;
    int m0 = blockIdx.x * 64, n0 = blockIdx.y * 64;
    int K8 = K >> 3;
    f32x4 acc[4][4];
    #pragma unroll
    for (int i = 0; i < 4; i++)
        #pragma unroll
        for (int j = 0; j < 4; j++) acc[i][j] = (f32x4){0.f, 0.f, 0.f, 0.f};

    const unsigned short* Ab = A  + (size_t)(m0 >> 4) * K8 * 128 + l * 8;
    const unsigned short* Bb = Bw + (size_t)(n0 >> 4) * K8 * 128 + l * 8;

    for (int k0 = 0; k0 < K; k0 += 32) {
        int koff = (k0 >> 3) * 128;
        #pragma unroll
        for (int i = 0; i < 4; i++) {
            gl_lds16(Ab + (size_t)i * K8 * 128 + koff, &aF[i * 64]);
            gl_lds16(Bb + (size_t)i * K8 * 128 + koff, &bF[i * 64]);
        }
        __syncthreads();
        bf16x8 av[4], bv[4];
        #pragma unroll
        for (int i = 0; i < 4; i++) av[i] = aF[i * 64 + l];
        #pragma unroll
        for (int j = 0; j < 4; j++) bv[j] = bF[j * 64 + l];
        #pragma unroll
        for (int i = 0; i < 4; i++)
            #pragma unroll
            for (int j = 0; j < 4; j++)
                acc[i][j] = __builtin_amdgcn_mfma_f32_16x16x32_bf16(av[i], bv[j], acc[i][j], 0, 0, 0);
        __syncthreads();
    }

    int col = l & 15;
    int rb = (l >> 4) * 4;
    if (mode == 2) {
        float* out = (float*)Cout;
        #pragma unroll
        for (int j = 0; j < 4; j++) {
            int n = n0 + j * 16 + col;
            float bj = bias[n];
            #pragma unroll
            for (int i = 0; i < 4; i++)
                #pragma unroll
                for (int r = 0; r < 4; r++) {
                    int mm = m0 + i * 16 + rb + r;
                    out[(size_t)mm * N + n] = acc[i][j][r] + bj + res[(size_t)mm * N + n];
                }
        }
    } else if (mode == 0) {
        unsigned short* out = (unsigned short*)Cout;
        #pragma unroll
        for (int j = 0; j < 4; j++) {
            int n = n0 + j * 16 + col;
            float bj = bias[n];
            #pragma unroll
            for (int i = 0; i < 4; i++)
                #pragma unroll
                for (int r = 0; r < 4; r++) {
                    int mm = m0 + i * 16 + rb + r;
                    out[(size_t)mm * N + n] = f2bf(acc[i][j][r] + bj);
                }
        }
    } else {
        unsigned short* out = (unsigned short*)Cout;
        int N8 = N >> 3;
        #pragma unroll
        for (int j = 0; j < 4; j++) {
            int n = n0 + j * 16 + col;
            float bj = bias[n];
            #pragma unroll
            for (int i = 0; i < 4; i++)
                #pragma unroll
                for (int r = 0; r < 4; r++) {
                    int mm = m0 + i * 16 + rb + r;
                    float v = acc[i][j][r] + bj;
                    v = 0.5f * v * (1.0f + erff(v * 0.70710678118f));
                    size_t ad = ((size_t)(mm >> 4) * N8 + (n >> 3)) * 128 + (mm & 15) * 8 + (n & 7);
                    out[ad] = f2bf(v);
                }
        }
    }
}

// ---------------------------------------------------------------------------
// Flash attention, bf16 in / bf16 A-swizzled out (K=768 layout).
// One block (256 thr) per (b, h, 64-row Q tile).
// ---------------------------------------------------------------------------
constexpr int QT = 64, KT = 64;

__global__ __launch_bounds__(256)
void fattn_kernel(const unsigned short* __restrict__ Qp, const unsigned short* __restrict__ Kp,
                  const unsigned short* __restrict__ Vp, unsigned short* __restrict__ O,
                  int q_stride, int kv_stride, float scale) {
    __shared__ float Qt[cHD][QT + 4];
    __shared__ float KV[KT][cHD + 4];
    __shared__ float Ps[QT][KT + 1];
    __shared__ float pred[QT][17];
    __shared__ float mrow[QT], lrow[QT], arow[QT];

    int t  = threadIdx.x;
    int tx = t & 15, ty = t >> 4;
    int blk = blockIdx.x;
    int qt0 = (blk & 15) * QT;
    int bh  = blk >> 4;
    int h   = bh % cH;
    int bb  = bh / cH;
    int lr = t >> 2, lq = t & 3;

    {
        const uint4* q4 = (const uint4*)(Qp + (size_t)(bb * cN + qt0 + lr) * q_stride + h * cHD + lq * 16);
        uint4 u0 = q4[0], u1 = q4[1];
        unsigned int uu[8] = {u0.x, u0.y, u0.z, u0.w, u1.x, u1.y, u1.z, u1.w};
        #pragma unroll
        for (int w = 0; w < 8; w++) {
            int d = lq * 16 + w * 2;
            Qt[d][lr]     = lo2f(uu[w]) * scale;
            Qt[d + 1][lr] = hi2f(uu[w]) * scale;
        }
    }
    if (t < QT) { mrow[t] = -1e30f; lrow[t] = 0.f; }
    float o[4][4] = {{0.f, 0.f, 0.f, 0.f}};
    __syncthreads();

    for (int kt0 = 0; kt0 < cN; kt0 += KT) {
        {
            const uint4* k4 = (const uint4*)(Kp + (size_t)(bb * cN + kt0 + lr) * kv_stride + h * cHD + lq * 16);
            uint4 u0 = k4[0], u1 = k4[1];
            unsigned int uu[8] = {u0.x, u0.y, u0.z, u0.w, u1.x, u1.y, u1.z, u1.w};
            #pragma unroll
            for (int w = 0; w < 8; w++) {
                int d = lq * 16 + w * 2;
                KV[d][lr]     = lo2f(uu[w]);
                KV[d + 1][lr] = hi2f(uu[w]);
            }
        }
        __syncthreads();

        float acc[4][4] = {{0.f}};
        #pragma unroll 4
        for (int d = 0; d < cHD; d++) {
            float4 a4 = *(const float4*)&Qt[d][ty * 4];
            float4 b4 = *(const float4*)&KV[d][tx * 4];
            float av[4] = {a4.x, a4.y, a4.z, a4.w};
            float bv[4] = {b4.x, b4.y, b4.z, b4.w};
            #pragma unroll
            for (int i = 0; i < 4; i++)
                #pragma unroll
                for (int j = 0; j < 4; j++)
                    acc[i][j] = fmaf(av[i], bv[j], acc[i][j]);
        }

        #pragma unroll
        for (int i = 0; i < 4; i++)
            pred[ty * 4 + i][tx] = fmaxf(fmaxf(acc[i][0], acc[i][1]),
                                         fmaxf(acc[i][2], acc[i][3]));
        __syncthreads();

        if (t < QT) {
            float tm = -1e30f;
            #pragma unroll
            for (int k = 0; k < 16; k++) tm = fmaxf(tm, pred[t][k]);
            float mo = mrow[t];
            float mn = fmaxf(mo, tm);
            mrow[t] = mn;
            arow[t] = __expf(mo - mn);
        }
        __syncthreads();

        #pragma unroll
        for (int i = 0; i < 4; i++) {
            int row = ty * 4 + i;
            float mn = mrow[row];
            float al = arow[row];
            float ps = 0.f;
            #pragma unroll
            for (int j = 0; j < 4; j++) {
                float p = __expf(acc[i][j] - mn);
                Ps[row][tx * 4 + j] = p;
                ps += p;
                o[i][j] *= al;
            }
            pred[row][tx] = ps;
        }
        {
            const uint4* v4 = (const uint4*)(Vp + (size_t)(bb * cN + kt0 + lr) * kv_stride + h * cHD + lq * 16);
            uint4 u0 = v4[0], u1 = v4[1];
            unsigned int uu[8] = {u0.x, u0.y, u0.z, u0.w, u1.x, u1.y, u1.z, u1.w};
            #pragma unroll
            for (int w = 0; w < 8; w++) {
                int d = lq * 16 + w * 2;
                KV[lr][d]     = lo2f(uu[w]);
                KV[lr][d + 1] = hi2f(uu[w]);
            }
        }
        __syncthreads();

        if (t < QT) {
            float s = 0.f;
            #pragma unroll
            for (int k = 0; k < 16; k++) s += pred[t][k];
            lrow[t] = lrow[t] * arow[t] + s;
        }
        #pragma unroll 4
        for (int c = 0; c < KT; c++) {
            float4 b4 = *(const float4*)&KV[c][tx * 4];
            #pragma unroll
            for (int i = 0; i < 4; i++) {
                float a = Ps[ty * 4 + i][c];
                o[i][0] = fmaf(a, b4.x, o[i][0]);
                o[i][1] = fmaf(a, b4.y, o[i][1]);
                o[i][2] = fmaf(a, b4.z, o[i][2]);
                o[i][3] = fmaf(a, b4.w, o[i][3]);
            }
        }
        __syncthreads();
    }

    #pragma unroll
    for (int i = 0; i < 4; i++) {
        int row = ty * 4 + i;
        float inv = 1.0f / lrow[row];
        size_t m = (size_t)bb * cN + qt0 + row;
        unsigned int p0 = f2bf(o[i][0] * inv) | ((unsigned)f2bf(o[i][1] * inv) << 16);
        unsigned int p1 = f2bf(o[i][2] * inv) | ((unsigned)f2bf(o[i][3] * inv) << 16);
        size_t ad = ((m >> 4) * 96 + h * 8 + (tx >> 1)) * 128 + (m & 15) * 8 + (tx & 1) * 4;
        *(uint2*)&O[ad] = make_uint2(p0, p1);
    }
}

// ---------------------------------------------------------------------------
extern "C" void kernel_launch(void* const* d_in, const int* in_sizes, int n_in,
                              void* d_out, int out_size, void* d_ws, size_t ws_size,
                              hipStream_t stream) {
    const float* img_tok  = (const float*)d_in[0];
    const float* evt_tok  = (const float*)d_in[1];
    const float* ln_q1_g  = (const float*)d_in[2];
    const float* ln_q1_b  = (const float*)d_in[3];
    const float* ln_kv1_g = (const float*)d_in[4];
    const float* ln_kv1_b = (const float*)d_in[5];
    const float* ln_q2_g  = (const float*)d_in[6];
    const float* ln_q2_b  = (const float*)d_in[7];
    const float* ln_kv2_g = (const float*)d_in[8];
    const float* ln_kv2_b = (const float*)d_in[9];
    const float* ln_mi_g  = (const float*)d_in[10];
    const float* ln_mi_b  = (const float*)d_in[11];
    const float* ln_me_g  = (const float*)d_in[12];
    const float* ln_me_b  = (const float*)d_in[13];
    const float* si_qkv_w  = (const float*)d_in[14];
    const float* si_qkv_b  = (const float*)d_in[15];
    const float* si_proj_w = (const float*)d_in[16];
    const float* si_proj_b = (const float*)d_in[17];
    const float* se_qkv_w  = (const float*)d_in[18];
    const float* se_qkv_b  = (const float*)d_in[19];
    const float* se_proj_w = (const float*)d_in[20];
    const float* se_proj_b = (const float*)d_in[21];
    const float* xei_q_w = (const float*)d_in[22];
    const float* xei_q_b = (const float*)d_in[23];
    const float* xei_k_w = (const float*)d_in[24];
    const float* xei_k_b = (const float*)d_in[25];
    const float* xei_v_w = (const float*)d_in[26];
    const float* xei_v_b = (const float*)d_in[27];
    const float* xei_p_w = (const float*)d_in[28];
    const float* xei_p_b = (const float*)d_in[29];
    const float* xie_q_w = (const float*)d_in[30];
    const float* xie_q_b = (const float*)d_in[31];
    const float* xie_k_w = (const float*)d_in[32];
    const float* xie_k_b = (const float*)d_in[33];
    const float* xie_v_w = (const float*)d_in[34];
    const float* xie_v_b = (const float*)d_in[35];
    const float* xie_p_w = (const float*)d_in[36];
    const float* xie_p_b = (const float*)d_in[37];
    const float* mi_fc1_w = (const float*)d_in[38];
    const float* mi_fc1_b = (const float*)d_in[39];
    const float* mi_fc2_w = (const float*)d_in[40];
    const float* mi_fc2_b = (const float*)d_in[41];
    const float* me_fc1_w = (const float*)d_in[42];
    const float* me_fc1_b = (const float*)d_in[43];
    const float* me_fc2_w = (const float*)d_in[44];
    const float* me_fc2_b = (const float*)d_in[45];

    const size_t U = (size_t)cBN * cD;               // 3,145,728
    unsigned short* wsb = (unsigned short*)d_ws;
    unsigned short* Wz  = wsb;                       // 18,874,368 elems
    unsigned short* LNo = wsb + 18874368;            // U
    unsigned short* AO  = LNo + U;                   // U
    unsigned short* T1  = AO + U;                    // U
    unsigned short* T2  = T1 + U;                    // U
    unsigned short* T3  = T2 + U;                    // U
    unsigned short* Hid = AO;                        // 4U alias (AO+T1+T2+T3)
    float* out_img = (float*)d_out;
    float* out_evt = out_img + U;

    // weight offsets (bf16 elems)
    const size_t O_SI_QKV = 0,        O_SE_QKV = 1769472;
    const size_t O_SI_P   = 3538944,  O_SE_P   = 4128768;
    const size_t O_XEI_Q  = 4718592,  O_XEI_K  = 5308416, O_XEI_V = 5898240, O_XEI_P = 6488064;
    const size_t O_XIE_Q  = 7077888,  O_XIE_K  = 7667712, O_XIE_V = 8257536, O_XIE_P = 8847360;
    const size_t O_MI_F1  = 9437184,  O_MI_F2  = 11796480;
    const size_t O_ME_F1  = 14155776, O_ME_F2  = 16515072;

    auto wc = [&](const float* w, size_t off, int K, int N) {
        hipLaunchKernelGGL(wconv_kernel, dim3(K / 64, N / 64), dim3(256), 0, stream,
                           w, Wz + off, K, N);
    };
    auto ln = [&](const float* x_, const float* g_, const float* b_, unsigned short* y_) {
        hipLaunchKernelGGL(ln_kernel, dim3(cBN / 16), dim3(256), 0, stream, x_, g_, b_, y_);
    };
    auto gemm = [&](const unsigned short* A_, size_t woff, const float* b_,
                    const float* r_, void* C_, int K_, int N_, int mode_) {
        hipLaunchKernelGGL(mfma_gemm, dim3(cBN / 64, N_ / 64), dim3(64), 0, stream,
                           A_, Wz + woff, b_, r_, C_, cBN, K_, N_, mode_);
    };
    auto attn = [&](const unsigned short* q_, const unsigned short* k_, const unsigned short* v_,
                    unsigned short* o_, int qs_, int kvs_, float sc_) {
        hipLaunchKernelGGL(fattn_kernel, dim3(cB * cH * (cN / QT)), dim3(256), 0, stream,
                           q_, k_, v_, o_, qs_, kvs_, sc_);
    };
    const float SC = 0.125f;

    // ---- weight conversion (every launch; ws is re-poisoned by harness)
    wc(si_qkv_w, O_SI_QKV, 768, 2304);  wc(se_qkv_w, O_SE_QKV, 768, 2304);
    wc(si_proj_w, O_SI_P, 768, 768);    wc(se_proj_w, O_SE_P, 768, 768);
    wc(xei_q_w, O_XEI_Q, 768, 768);     wc(xei_k_w, O_XEI_K, 768, 768);
    wc(xei_v_w, O_XEI_V, 768, 768);     wc(xei_p_w, O_XEI_P, 768, 768);
    wc(xie_q_w, O_XIE_Q, 768, 768);     wc(xie_k_w, O_XIE_K, 768, 768);
    wc(xie_v_w, O_XIE_V, 768, 768);     wc(xie_p_w, O_XIE_P, 768, 768);
    wc(mi_fc1_w, O_MI_F1, 768, 3072);   wc(mi_fc2_w, O_MI_F2, 3072, 768);
    wc(me_fc1_w, O_ME_F1, 768, 3072);   wc(me_fc2_w, O_ME_F2, 3072, 768);

    // ---- self-attn img
    ln(img_tok, ln_q1_g, ln_q1_b, LNo);
    gemm(LNo, O_SI_QKV, si_qkv_b, nullptr, T1, 768, 2304, 0);
    attn(T1, T1 + 768, T1 + 1536, AO, 2304, 2304, SC);
    gemm(AO, O_SI_P, si_proj_b, img_tok, out_img, 768, 768, 2);

    // ---- self-attn evt
    ln(evt_tok, ln_kv1_g, ln_kv1_b, LNo);
    gemm(LNo, O_SE_QKV, se_qkv_b, nullptr, T1, 768, 2304, 0);
    attn(T1, T1 + 768, T1 + 1536, AO, 2304, 2304, SC);
    gemm(AO, O_SE_P, se_proj_b, evt_tok, out_evt, 768, 768, 2);

    // ---- cross xei: q=ln_q2(i1), kv=ln_kv2(e1), negated
    ln(out_img, ln_q2_g, ln_q2_b, LNo);
    gemm(LNo, O_XEI_Q, xei_q_b, nullptr, T1, 768, 768, 0);
    ln(out_evt, ln_kv2_g, ln_kv2_b, LNo);
    gemm(LNo, O_XEI_K, xei_k_b, nullptr, T2, 768, 768, 0);
    gemm(LNo, O_XEI_V, xei_v_b, nullptr, T3, 768, 768, 0);
    attn(T1, T2, T3, AO, 768, 768, -SC);

    // xie inputs while i1/e1 intact
    ln(out_img, ln_kv2_g, ln_kv2_b, LNo);
    gemm(LNo, O_XIE_K, xie_k_b, nullptr, T1, 768, 768, 0);
    gemm(LNo, O_XIE_V, xie_v_b, nullptr, T2, 768, 768, 0);
    ln(out_evt, ln_q2_g, ln_q2_b, LNo);
    gemm(LNo, O_XIE_Q, xie_q_b, nullptr, T3, 768, 768, 0);

    gemm(AO, O_XEI_P, xei_p_b, out_img, out_img, 768, 768, 2);   // i2
    attn(T3, T1, T2, AO, 768, 768, -SC);
    gemm(AO, O_XIE_P, xie_p_b, out_evt, out_evt, 768, 768, 2);   // e2

    // ---- MLP img
    ln(out_img, ln_mi_g, ln_mi_b, LNo);
    gemm(LNo, O_MI_F1, mi_fc1_b, nullptr, Hid, 768, 3072, 1);
    gemm(Hid, O_MI_F2, mi_fc2_b, out_img, out_img, 3072, 768, 2);

    // ---- MLP evt
    ln(out_evt, ln_me_g, ln_me_b, LNo);
    gemm(LNo, O_ME_F1, me_fc1_b, nullptr, Hid, 768, 3072, 1);
    gemm(Hid, O_ME_F2, me_fc2_b, out_evt, out_evt, 3072, 768, 2);
}

// Round 5
// 1145.293 us; speedup vs baseline: 14.1306x; 1.4300x over previous
//
#include <hip/hip_runtime.h>

constexpr int cB  = 4;
constexpr int cN  = 1024;
constexpr int cD  = 768;
constexpr int cH  = 12;
constexpr int cHD = 64;
constexpr int cHID = 3072;
constexpr int cBN = cB * cN;   // 4096 rows

typedef unsigned short ushort_t;
typedef __attribute__((ext_vector_type(8))) short bf16x8;
typedef __attribute__((ext_vector_type(4))) float f32x4;

static __device__ __forceinline__ unsigned short f2bf(float f) {
    union { float f; unsigned int u; } v; v.f = f;
    unsigned int u = v.u;
    return (unsigned short)((u + 0x7FFFu + ((u >> 16) & 1u)) >> 16);
}

static __device__ __forceinline__ void gl_lds16(const void* g, void* l) {
    __builtin_amdgcn_global_load_lds(
        (const __attribute__((address_space(1))) unsigned int*)g,
        (__attribute__((address_space(3))) unsigned int*)l, 16, 0, 0);
}

// ---------------------------------------------------------------------------
// Weight convert: W fp32 [K][N] row-major -> bf16 B-swizzled:
//   elem(n,k) at ((n>>4)*(K/8)+(k>>3))*128 + (n&15)*8 + (k&7)
// ---------------------------------------------------------------------------
__global__ __launch_bounds__(256)
void wconv_kernel(const float* __restrict__ W, unsigned short* __restrict__ Wo,
                  int K, int N) {
    __shared__ float Ls[64][68];
    int k0 = blockIdx.x * 64, n0 = blockIdx.y * 64;
    int t = threadIdx.x;
    int lr = t >> 4, lc = (t & 15) * 4;
    #pragma unroll
    for (int i = 0; i < 4; i++) {
        float4 v = *(const float4*)&W[(size_t)(k0 + lr + i * 16) * N + n0 + lc];
        Ls[lr + i * 16][lc + 0] = v.x;  Ls[lr + i * 16][lc + 1] = v.y;
        Ls[lr + i * 16][lc + 2] = v.z;  Ls[lr + i * 16][lc + 3] = v.w;
    }
    __syncthreads();
    int mt = t >> 3;
    int nb = mt & 3, kb = mt >> 2;
    int sub = t & 7;
    int K8 = K >> 3;
    size_t chunk = ((size_t)(n0 / 16 + nb) * K8 + (size_t)(k0 / 8 + kb)) * 128;
    unsigned short buf[16];
    #pragma unroll
    for (int rr = 0; rr < 2; rr++) {
        int n_r = sub * 2 + rr;
        #pragma unroll
        for (int kk = 0; kk < 8; kk++)
            buf[rr * 8 + kk] = f2bf(Ls[kb * 8 + kk][nb * 16 + n_r]);
    }
    uint4 w0, w1;
    w0.x = buf[0] | ((unsigned)buf[1] << 16);   w0.y = buf[2] | ((unsigned)buf[3] << 16);
    w0.z = buf[4] | ((unsigned)buf[5] << 16);   w0.w = buf[6] | ((unsigned)buf[7] << 16);
    w1.x = buf[8] | ((unsigned)buf[9] << 16);   w1.y = buf[10] | ((unsigned)buf[11] << 16);
    w1.z = buf[12] | ((unsigned)buf[13] << 16); w1.w = buf[14] | ((unsigned)buf[15] << 16);
    *(uint4*)&Wo[chunk + sub * 16]     = w0;
    *(uint4*)&Wo[chunk + sub * 16 + 8] = w1;
}

// ---------------------------------------------------------------------------
// LayerNorm: fp32 in -> bf16 A-swizzled out (K=768 layout).
// ---------------------------------------------------------------------------
__global__ __launch_bounds__(256)
void ln_kernel(const float* __restrict__ x, const float* __restrict__ g,
               const float* __restrict__ b, unsigned short* __restrict__ y) {
    __shared__ float psum[16][17], psq[16][17];
    __shared__ float mean_s[16], rstd_s[16];
    int R = blockIdx.x;
    int t = threadIdx.x;
    int r = t >> 4, c16 = t & 15;
    const float* xr = x + ((size_t)R * 16 + r) * cD;
    float s = 0.f, sq = 0.f;
    #pragma unroll
    for (int i = 0; i < 12; i++) {
        float4 v = *(const float4*)&xr[c16 * 4 + i * 64];
        s  += v.x + v.y + v.z + v.w;
        sq += v.x * v.x + v.y * v.y + v.z * v.z + v.w * v.w;
    }
    psum[r][c16] = s; psq[r][c16] = sq;
    __syncthreads();
    if (t < 16) {
        float ss = 0.f, qq = 0.f;
        #pragma unroll
        for (int i = 0; i < 16; i++) { ss += psum[t][i]; qq += psq[t][i]; }
        float m = ss / (float)cD;
        mean_s[t] = m;
        rstd_s[t] = rsqrtf(qq / (float)cD - m * m + 1e-5f);
    }
    __syncthreads();
    int r2 = t & 15, cslot = t >> 4;
    const float* xr2 = x + ((size_t)R * 16 + r2) * cD;
    float m = mean_s[r2], rs = rstd_s[r2];
    for (int c = cslot; c < 96; c += 16) {
        float4 a0 = *(const float4*)&xr2[c * 8];
        float4 a1 = *(const float4*)&xr2[c * 8 + 4];
        float4 g0 = *(const float4*)&g[c * 8];
        float4 g1 = *(const float4*)&g[c * 8 + 4];
        float4 b0 = *(const float4*)&b[c * 8];
        float4 b1 = *(const float4*)&b[c * 8 + 4];
        unsigned short o[8];
        o[0] = f2bf((a0.x - m) * rs * g0.x + b0.x);
        o[1] = f2bf((a0.y - m) * rs * g0.y + b0.y);
        o[2] = f2bf((a0.z - m) * rs * g0.z + b0.z);
        o[3] = f2bf((a0.w - m) * rs * g0.w + b0.w);
        o[4] = f2bf((a1.x - m) * rs * g1.x + b1.x);
        o[5] = f2bf((a1.y - m) * rs * g1.y + b1.y);
        o[6] = f2bf((a1.z - m) * rs * g1.z + b1.z);
        o[7] = f2bf((a1.w - m) * rs * g1.w + b1.w);
        uint4 w;
        w.x = o[0] | ((unsigned)o[1] << 16); w.y = o[2] | ((unsigned)o[3] << 16);
        w.z = o[4] | ((unsigned)o[5] << 16); w.w = o[6] | ((unsigned)o[7] << 16);
        *(uint4*)&y[((size_t)R * 96 + c) * 128 + r2 * 8] = w;
    }
}

// ---------------------------------------------------------------------------
// MFMA GEMM. A bf16 A-swizzled; W bf16 B-swizzled. 64x64 tile / 1-wave block.
// modes: 0 row-major bf16 (ostride). 1: A-swizzled + GELU. 2: fp32 + res.
//        3: packed QKV (n<1536 row-major; V part -> Vt). 4: all cols -> Vt.
// Vt layout: [b*12+h][d=0..63][tok=0..1023] bf16.
// ---------------------------------------------------------------------------
__global__ __launch_bounds__(64)
void mfma_gemm(const unsigned short* __restrict__ A,
               const unsigned short* __restrict__ Bw,
               const float* __restrict__ bias, const float* __restrict__ res,
               void* __restrict__ Cout, unsigned short* __restrict__ VtOut,
               int M, int K, int N, int ostride, int mode) {
    __shared__ bf16x8 aF[4 * 64];
    __shared__ bf16x8 bF[4 * 64];
    int l = threadIdx.x;
    int m0 = blockIdx.x * 64, n0 = blockIdx.y * 64;
    int K8 = K >> 3;
    f32x4 acc[4][4];
    #pragma unroll
    for (int i = 0; i < 4; i++)
        #pragma unroll
        for (int j = 0; j < 4; j++) acc[i][j] = (f32x4){0.f, 0.f, 0.f, 0.f};

    const unsigned short* Ab = A  + (size_t)(m0 >> 4) * K8 * 128 + l * 8;
    const unsigned short* Bb = Bw + (size_t)(n0 >> 4) * K8 * 128 + l * 8;

    for (int k0 = 0; k0 < K; k0 += 32) {
        int koff = (k0 >> 3) * 128;
        #pragma unroll
        for (int i = 0; i < 4; i++) {
            gl_lds16(Ab + (size_t)i * K8 * 128 + koff, &aF[i * 64]);
            gl_lds16(Bb + (size_t)i * K8 * 128 + koff, &bF[i * 64]);
        }
        __syncthreads();
        bf16x8 av[4], bv[4];
        #pragma unroll
        for (int i = 0; i < 4; i++) av[i] = aF[i * 64 + l];
        #pragma unroll
        for (int j = 0; j < 4; j++) bv[j] = bF[j * 64 + l];
        #pragma unroll
        for (int i = 0; i < 4; i++)
            #pragma unroll
            for (int j = 0; j < 4; j++)
                acc[i][j] = __builtin_amdgcn_mfma_f32_16x16x32_bf16(av[i], bv[j], acc[i][j], 0, 0, 0);
        __syncthreads();
    }

    int col = l & 15;
    int rb = (l >> 4) * 4;
    if (mode == 2) {
        float* out = (float*)Cout;
        #pragma unroll
        for (int j = 0; j < 4; j++) {
            int n = n0 + j * 16 + col;
            float bj = bias[n];
            #pragma unroll
            for (int i = 0; i < 4; i++)
                #pragma unroll
                for (int r = 0; r < 4; r++) {
                    int mm = m0 + i * 16 + rb + r;
                    out[(size_t)mm * ostride + n] = acc[i][j][r] + bj + res[(size_t)mm * ostride + n];
                }
        }
    } else if (mode == 1) {
        unsigned short* out = (unsigned short*)Cout;
        int N8 = N >> 3;
        #pragma unroll
        for (int j = 0; j < 4; j++) {
            int n = n0 + j * 16 + col;
            float bj = bias[n];
            #pragma unroll
            for (int i = 0; i < 4; i++)
                #pragma unroll
                for (int r = 0; r < 4; r++) {
                    int mm = m0 + i * 16 + rb + r;
                    float v = acc[i][j][r] + bj;
                    v = 0.5f * v * (1.0f + erff(v * 0.70710678118f));
                    size_t ad = ((size_t)(mm >> 4) * N8 + (n >> 3)) * 128 + (mm & 15) * 8 + (n & 7);
                    out[ad] = f2bf(v);
                }
        }
    } else {
        bool toVt = (mode == 4) || (mode == 3 && n0 >= 1536);
        if (!toVt) {
            unsigned short* out = (unsigned short*)Cout;
            #pragma unroll
            for (int j = 0; j < 4; j++) {
                int n = n0 + j * 16 + col;
                float bj = bias[n];
                #pragma unroll
                for (int i = 0; i < 4; i++)
                    #pragma unroll
                    for (int r = 0; r < 4; r++) {
                        int mm = m0 + i * 16 + rb + r;
                        out[(size_t)mm * ostride + n] = f2bf(acc[i][j][r] + bj);
                    }
            }
        } else {
            int vbase = (mode == 3) ? 1536 : 0;
            #pragma unroll
            for (int j = 0; j < 4; j++) {
                int n = n0 + j * 16 + col;
                float bj = bias[n];
                int vc = n - vbase;
                int ph = vc >> 6, d = vc & 63;
                #pragma unroll
                for (int i = 0; i < 4; i++) {
                    int mm = m0 + i * 16 + rb;
                    int bbv = mm >> 10, tok = mm & 1023;
                    unsigned short q0 = f2bf(acc[i][j][0] + bj);
                    unsigned short q1 = f2bf(acc[i][j][1] + bj);
                    unsigned short q2 = f2bf(acc[i][j][2] + bj);
                    unsigned short q3 = f2bf(acc[i][j][3] + bj);
                    uint2 pk;
                    pk.x = q0 | ((unsigned)q1 << 16);
                    pk.y = q2 | ((unsigned)q3 << 16);
                    size_t ad = ((size_t)(bbv * 12 + ph) * 64 + d) * 1024 + tok;
                    *(uint2*)&VtOut[ad] = pk;
                }
            }
        }
    }
}

// ---------------------------------------------------------------------------
// MFMA flash attention. Block = 256 thr = 4 independent waves; wave w owns
// q-rows qt0+16w..+15. Zero __syncthreads. Q/K frags gathered per-lane from
// row-major bf16 (stride qk_stride); V frags from pre-transposed Vt planes.
// P C->A layout transform via wave-private LDS (lgkmcnt guard only).
// Output: A-swizzled bf16 (K=768 layout) for the projection GEMM.
// ---------------------------------------------------------------------------
__global__ __launch_bounds__(256)
void fattn_kernel(const unsigned short* __restrict__ Qp,
                  const unsigned short* __restrict__ Kp,
                  const unsigned short* __restrict__ Vt,
                  unsigned short* __restrict__ O,
                  int qk_stride, float scale) {
    __shared__ unsigned short Ps[4][16][72];

    int t = threadIdx.x;
    int w = t >> 6, l = t & 63;
    int la = l & 15, lb = l >> 4;
    int blk = blockIdx.x;
    int qt0 = (blk & 15) * 64 + w * 16;
    int bh = blk >> 4;
    int h = bh % cH, bb = bh / cH;

    const unsigned short* Qb = Qp + (size_t)(bb * cN) * qk_stride + h * cHD;
    const unsigned short* Kb = Kp + (size_t)(bb * cN) * qk_stride + h * cHD;
    const unsigned short* Vb = Vt + (size_t)(bb * cH + h) * (64 * 1024);

    bf16x8 av[2];
    #pragma unroll
    for (int s = 0; s < 2; s++)
        av[s] = *(const bf16x8*)(Qb + (size_t)(qt0 + la) * qk_stride + 32 * s + 8 * lb);

    float m_run[4], l_run[4];
    f32x4 acc_o[4];
    #pragma unroll
    for (int r = 0; r < 4; r++) { m_run[r] = -1e30f; l_run[r] = 0.f; }
    #pragma unroll
    for (int nt = 0; nt < 4; nt++) acc_o[nt] = (f32x4){0.f, 0.f, 0.f, 0.f};

    for (int kt0 = 0; kt0 < cN; kt0 += 64) {
        // ---- S = Q K^T (B-frags gathered from row-major K)
        bf16x8 kf[4][2];
        #pragma unroll
        for (int j = 0; j < 4; j++)
            #pragma unroll
            for (int s = 0; s < 2; s++)
                kf[j][s] = *(const bf16x8*)(Kb + (size_t)(kt0 + 16 * j + la) * qk_stride + 32 * s + 8 * lb);
        f32x4 sj[4];
        #pragma unroll
        for (int j = 0; j < 4; j++) sj[j] = (f32x4){0.f, 0.f, 0.f, 0.f};
        #pragma unroll
        for (int j = 0; j < 4; j++)
            #pragma unroll
            for (int s = 0; s < 2; s++)
                sj[j] = __builtin_amdgcn_mfma_f32_16x16x32_bf16(av[s], kf[j][s], sj[j], 0, 0, 0);

        // ---- online softmax in registers (rows 4*lb+r of this wave's 16)
        float x[4][4];
        #pragma unroll
        for (int j = 0; j < 4; j++)
            #pragma unroll
            for (int r = 0; r < 4; r++) x[j][r] = sj[j][r] * scale;
        float mt[4];
        #pragma unroll
        for (int r = 0; r < 4; r++)
            mt[r] = fmaxf(fmaxf(x[0][r], x[1][r]), fmaxf(x[2][r], x[3][r]));
        #pragma unroll
        for (int off = 1; off <= 8; off <<= 1)
            #pragma unroll
            for (int r = 0; r < 4; r++)
                mt[r] = fmaxf(mt[r], __shfl_xor(mt[r], off, 64));
        float al[4];
        #pragma unroll
        for (int r = 0; r < 4; r++) {
            float mn = fmaxf(m_run[r], mt[r]);
            al[r] = __expf(m_run[r] - mn);
            m_run[r] = mn;
        }
        float p[4][4], ts[4] = {0.f, 0.f, 0.f, 0.f};
        #pragma unroll
        for (int j = 0; j < 4; j++)
            #pragma unroll
            for (int r = 0; r < 4; r++) {
                p[j][r] = __expf(x[j][r] - m_run[r]);
                ts[r] += p[j][r];
            }
        #pragma unroll
        for (int off = 1; off <= 8; off <<= 1)
            #pragma unroll
            for (int r = 0; r < 4; r++)
                ts[r] += __shfl_xor(ts[r], off, 64);
        #pragma unroll
        for (int r = 0; r < 4; r++) l_run[r] = l_run[r] * al[r] + ts[r];
        #pragma unroll
        for (int nt = 0; nt < 4; nt++)
            #pragma unroll
            for (int r = 0; r < 4; r++) acc_o[nt][r] *= al[r];

        // ---- P: C-layout regs -> wave-private LDS -> A-frags
        #pragma unroll
        for (int j = 0; j < 4; j++)
            #pragma unroll
            for (int r = 0; r < 4; r++)
                Ps[w][lb * 4 + r][16 * j + la] = f2bf(p[j][r]);
        asm volatile("s_waitcnt lgkmcnt(0)" ::: "memory");
        bf16x8 pf[2];
        #pragma unroll
        for (int s = 0; s < 2; s++)
            pf[s] = *(const bf16x8*)&Ps[w][la][32 * s + 8 * lb];

        // ---- O += P V (B-frags from Vt planes: contiguous along tok)
        #pragma unroll
        for (int nt = 0; nt < 4; nt++)
            #pragma unroll
            for (int s = 0; s < 2; s++) {
                bf16x8 vf = *(const bf16x8*)(Vb + (size_t)(16 * nt + la) * 1024 + kt0 + 32 * s + 8 * lb);
                acc_o[nt] = __builtin_amdgcn_mfma_f32_16x16x32_bf16(pf[s], vf, acc_o[nt], 0, 0, 0);
            }
    }

    // ---- epilogue: O/l, A-swizzled store (K=768 layout)
    float inv[4];
    #pragma unroll
    for (int r = 0; r < 4; r++) inv[r] = 1.0f / l_run[r];
    size_t mhi = ((size_t)bb * cN + qt0) >> 4;   // uniform
    #pragma unroll
    for (int nt = 0; nt < 4; nt++) {
        int k = h * cHD + 16 * nt + la;
        size_t base = (mhi * 96 + (k >> 3)) * 128 + (k & 7);
        #pragma unroll
        for (int r = 0; r < 4; r++) {
            unsigned short val = f2bf(acc_o[nt][r] * inv[r]);
            O[base + (lb * 4 + r) * 8] = val;
        }
    }
}

// ---------------------------------------------------------------------------
extern "C" void kernel_launch(void* const* d_in, const int* in_sizes, int n_in,
                              void* d_out, int out_size, void* d_ws, size_t ws_size,
                              hipStream_t stream) {
    const float* img_tok  = (const float*)d_in[0];
    const float* evt_tok  = (const float*)d_in[1];
    const float* ln_q1_g  = (const float*)d_in[2];
    const float* ln_q1_b  = (const float*)d_in[3];
    const float* ln_kv1_g = (const float*)d_in[4];
    const float* ln_kv1_b = (const float*)d_in[5];
    const float* ln_q2_g  = (const float*)d_in[6];
    const float* ln_q2_b  = (const float*)d_in[7];
    const float* ln_kv2_g = (const float*)d_in[8];
    const float* ln_kv2_b = (const float*)d_in[9];
    const float* ln_mi_g  = (const float*)d_in[10];
    const float* ln_mi_b  = (const float*)d_in[11];
    const float* ln_me_g  = (const float*)d_in[12];
    const float* ln_me_b  = (const float*)d_in[13];
    const float* si_qkv_w  = (const float*)d_in[14];
    const float* si_qkv_b  = (const float*)d_in[15];
    const float* si_proj_w = (const float*)d_in[16];
    const float* si_proj_b = (const float*)d_in[17];
    const float* se_qkv_w  = (const float*)d_in[18];
    const float* se_qkv_b  = (const float*)d_in[19];
    const float* se_proj_w = (const float*)d_in[20];
    const float* se_proj_b = (const float*)d_in[21];
    const float* xei_q_w = (const float*)d_in[22];
    const float* xei_q_b = (const float*)d_in[23];
    const float* xei_k_w = (const float*)d_in[24];
    const float* xei_k_b = (const float*)d_in[25];
    const float* xei_v_w = (const float*)d_in[26];
    const float* xei_v_b = (const float*)d_in[27];
    const float* xei_p_w = (const float*)d_in[28];
    const float* xei_p_b = (const float*)d_in[29];
    const float* xie_q_w = (const float*)d_in[30];
    const float* xie_q_b = (const float*)d_in[31];
    const float* xie_k_w = (const float*)d_in[32];
    const float* xie_k_b = (const float*)d_in[33];
    const float* xie_v_w = (const float*)d_in[34];
    const float* xie_v_b = (const float*)d_in[35];
    const float* xie_p_w = (const float*)d_in[36];
    const float* xie_p_b = (const float*)d_in[37];
    const float* mi_fc1_w = (const float*)d_in[38];
    const float* mi_fc1_b = (const float*)d_in[39];
    const float* mi_fc2_w = (const float*)d_in[40];
    const float* mi_fc2_b = (const float*)d_in[41];
    const float* me_fc1_w = (const float*)d_in[42];
    const float* me_fc1_b = (const float*)d_in[43];
    const float* me_fc2_w = (const float*)d_in[44];
    const float* me_fc2_b = (const float*)d_in[45];

    const size_t U = (size_t)cBN * cD;               // 3,145,728
    unsigned short* wsb = (unsigned short*)d_ws;
    unsigned short* Wz  = wsb;                       // 18,874,368 elems
    unsigned short* LNo = wsb + 18874368;            // U
    unsigned short* AO  = LNo + U;                   // U
    unsigned short* T1  = AO + U;                    // 3U (row stride 2304)
    unsigned short* Vt  = T1 + 3 * U;                // U  [48][64][1024]
    unsigned short* Hid = AO;                        // 4U alias (AO + T1)
    float* out_img = (float*)d_out;
    float* out_evt = out_img + U;

    const size_t O_SI_QKV = 0,        O_SE_QKV = 1769472;
    const size_t O_SI_P   = 3538944,  O_SE_P   = 4128768;
    const size_t O_XEI_Q  = 4718592,  O_XEI_K  = 5308416, O_XEI_V = 5898240, O_XEI_P = 6488064;
    const size_t O_XIE_Q  = 7077888,  O_XIE_K  = 7667712, O_XIE_V = 8257536, O_XIE_P = 8847360;
    const size_t O_MI_F1  = 9437184,  O_MI_F2  = 11796480;
    const size_t O_ME_F1  = 14155776, O_ME_F2  = 16515072;

    auto wc = [&](const float* w, size_t off, int K, int N) {
        hipLaunchKernelGGL(wconv_kernel, dim3(K / 64, N / 64), dim3(256), 0, stream,
                           w, Wz + off, K, N);
    };
    auto ln = [&](const float* x_, const float* g_, const float* b_, unsigned short* y_) {
        hipLaunchKernelGGL(ln_kernel, dim3(cBN / 16), dim3(256), 0, stream, x_, g_, b_, y_);
    };
    auto gemm = [&](const unsigned short* A_, size_t woff, const float* b_,
                    const float* r_, void* C_, int K_, int N_, int ostride_, int mode_) {
        hipLaunchKernelGGL(mfma_gemm, dim3(cBN / 64, N_ / 64), dim3(64), 0, stream,
                           A_, Wz + woff, b_, r_, C_, Vt, cBN, K_, N_, ostride_, mode_);
    };
    auto attn = [&](const unsigned short* q_, const unsigned short* k_,
                    unsigned short* o_, float sc_) {
        hipLaunchKernelGGL(fattn_kernel, dim3(cB * cH * 16), dim3(256), 0, stream,
                           q_, k_, Vt, o_, 2304, sc_);
    };
    const float SC = 0.125f;

    // ---- weight conversion
    wc(si_qkv_w, O_SI_QKV, 768, 2304);  wc(se_qkv_w, O_SE_QKV, 768, 2304);
    wc(si_proj_w, O_SI_P, 768, 768);    wc(se_proj_w, O_SE_P, 768, 768);
    wc(xei_q_w, O_XEI_Q, 768, 768);     wc(xei_k_w, O_XEI_K, 768, 768);
    wc(xei_v_w, O_XEI_V, 768, 768);     wc(xei_p_w, O_XEI_P, 768, 768);
    wc(xie_q_w, O_XIE_Q, 768, 768);     wc(xie_k_w, O_XIE_K, 768, 768);
    wc(xie_v_w, O_XIE_V, 768, 768);     wc(xie_p_w, O_XIE_P, 768, 768);
    wc(mi_fc1_w, O_MI_F1, 768, 3072);   wc(mi_fc2_w, O_MI_F2, 3072, 768);
    wc(me_fc1_w, O_ME_F1, 768, 3072);   wc(me_fc2_w, O_ME_F2, 3072, 768);

    // ---- self-attn img
    ln(img_tok, ln_q1_g, ln_q1_b, LNo);
    gemm(LNo, O_SI_QKV, si_qkv_b, nullptr, T1, 768, 2304, 2304, 3);
    attn(T1, T1 + 768, AO, SC);
    gemm(AO, O_SI_P, si_proj_b, img_tok, out_img, 768, 768, 768, 2);

    // ---- self-attn evt
    ln(evt_tok, ln_kv1_g, ln_kv1_b, LNo);
    gemm(LNo, O_SE_QKV, se_qkv_b, nullptr, T1, 768, 2304, 2304, 3);
    attn(T1, T1 + 768, AO, SC);
    gemm(AO, O_SE_P, se_proj_b, evt_tok, out_evt, 768, 768, 768, 2);

    // ---- cross xei: q=ln_q2(i1), kv=ln_kv2(e1), negated
    ln(out_img, ln_q2_g, ln_q2_b, LNo);
    gemm(LNo, O_XEI_Q, xei_q_b, nullptr, T1, 768, 768, 2304, 0);
    ln(out_evt, ln_kv2_g, ln_kv2_b, LNo);
    gemm(LNo, O_XEI_K, xei_k_b, nullptr, T1 + 768, 768, 768, 2304, 0);
    gemm(LNo, O_XEI_V, xei_v_b, nullptr, T1, 768, 768, 2304, 4);       // -> Vt
    attn(T1, T1 + 768, AO, -SC);

    // ---- xie inputs while i1/e1 intact (attn above already consumed T1/Vt)
    ln(out_img, ln_kv2_g, ln_kv2_b, LNo);
    gemm(LNo, O_XIE_K, xie_k_b, nullptr, T1 + 768, 768, 768, 2304, 0);
    gemm(LNo, O_XIE_V, xie_v_b, nullptr, T1, 768, 768, 2304, 4);       // -> Vt
    ln(out_evt, ln_q2_g, ln_q2_b, LNo);
    gemm(LNo, O_XIE_Q, xie_q_b, nullptr, T1, 768, 768, 2304, 0);

    gemm(AO, O_XEI_P, xei_p_b, out_img, out_img, 768, 768, 768, 2);    // i2
    attn(T1, T1 + 768, AO, -SC);
    gemm(AO, O_XIE_P, xie_p_b, out_evt, out_evt, 768, 768, 768, 2);    // e2

    // ---- MLP img
    ln(out_img, ln_mi_g, ln_mi_b, LNo);
    gemm(LNo, O_MI_F1, mi_fc1_b, nullptr, Hid, 768, 3072, 3072, 1);
    gemm(Hid, O_MI_F2, mi_fc2_b, out_img, out_img, 3072, 768, 768, 2);

    // ---- MLP evt
    ln(out_evt, ln_me_g, ln_me_b, LNo);
    gemm(LNo, O_ME_F1, me_fc1_b, nullptr, Hid, 768, 3072, 3072, 1);
    gemm(Hid, O_ME_F2, me_fc2_b, out_evt, out_evt, 3072, 768, 768, 2);
}

// Round 6
// 1080.354 us; speedup vs baseline: 14.9800x; 1.0601x over previous
//
#include <hip/hip_runtime.h>

constexpr int cB  = 4;
constexpr int cN  = 1024;
constexpr int cD  = 768;
constexpr int cH  = 12;
constexpr int cHD = 64;
constexpr int cHID = 3072;
constexpr int cBN = cB * cN;   // 4096 rows

typedef __attribute__((ext_vector_type(8))) short bf16x8;
typedef __attribute__((ext_vector_type(4))) float f32x4;

static __device__ __forceinline__ unsigned short f2bf(float f) {
    union { float f; unsigned int u; } v; v.f = f;
    unsigned int u = v.u;
    return (unsigned short)((u + 0x7FFFu + ((u >> 16) & 1u)) >> 16);
}

static __device__ __forceinline__ void gl_lds16(const void* g, void* l) {
    __builtin_amdgcn_global_load_lds(
        (const __attribute__((address_space(1))) unsigned int*)g,
        (__attribute__((address_space(3))) unsigned int*)l, 16, 0, 0);
}

// ---------------------------------------------------------------------------
// Weight convert: W fp32 [K][N] row-major -> bf16 B-swizzled:
//   elem(n,k) at ((n>>4)*(K/8)+(k>>3))*128 + (n&15)*8 + (k&7)
// ---------------------------------------------------------------------------
__global__ __launch_bounds__(256)
void wconv_kernel(const float* __restrict__ W, unsigned short* __restrict__ Wo,
                  int K, int N) {
    __shared__ float Ls[64][68];
    int k0 = blockIdx.x * 64, n0 = blockIdx.y * 64;
    int t = threadIdx.x;
    int lr = t >> 4, lc = (t & 15) * 4;
    #pragma unroll
    for (int i = 0; i < 4; i++) {
        float4 v = *(const float4*)&W[(size_t)(k0 + lr + i * 16) * N + n0 + lc];
        Ls[lr + i * 16][lc + 0] = v.x;  Ls[lr + i * 16][lc + 1] = v.y;
        Ls[lr + i * 16][lc + 2] = v.z;  Ls[lr + i * 16][lc + 3] = v.w;
    }
    __syncthreads();
    int mt = t >> 3;
    int nb = mt & 3, kb = mt >> 2;
    int sub = t & 7;
    int K8 = K >> 3;
    size_t chunk = ((size_t)(n0 / 16 + nb) * K8 + (size_t)(k0 / 8 + kb)) * 128;
    unsigned short buf[16];
    #pragma unroll
    for (int rr = 0; rr < 2; rr++) {
        int n_r = sub * 2 + rr;
        #pragma unroll
        for (int kk = 0; kk < 8; kk++)
            buf[rr * 8 + kk] = f2bf(Ls[kb * 8 + kk][nb * 16 + n_r]);
    }
    uint4 w0, w1;
    w0.x = buf[0] | ((unsigned)buf[1] << 16);   w0.y = buf[2] | ((unsigned)buf[3] << 16);
    w0.z = buf[4] | ((unsigned)buf[5] << 16);   w0.w = buf[6] | ((unsigned)buf[7] << 16);
    w1.x = buf[8] | ((unsigned)buf[9] << 16);   w1.y = buf[10] | ((unsigned)buf[11] << 16);
    w1.z = buf[12] | ((unsigned)buf[13] << 16); w1.w = buf[14] | ((unsigned)buf[15] << 16);
    *(uint4*)&Wo[chunk + sub * 16]     = w0;
    *(uint4*)&Wo[chunk + sub * 16 + 8] = w1;
}

// ---------------------------------------------------------------------------
// LayerNorm: fp32 in -> bf16 A-swizzled out (K=768 layout).
// ---------------------------------------------------------------------------
__global__ __launch_bounds__(256)
void ln_kernel(const float* __restrict__ x, const float* __restrict__ g,
               const float* __restrict__ b, unsigned short* __restrict__ y) {
    __shared__ float psum[16][17], psq[16][17];
    __shared__ float mean_s[16], rstd_s[16];
    int R = blockIdx.x;
    int t = threadIdx.x;
    int r = t >> 4, c16 = t & 15;
    const float* xr = x + ((size_t)R * 16 + r) * cD;
    float s = 0.f, sq = 0.f;
    #pragma unroll
    for (int i = 0; i < 12; i++) {
        float4 v = *(const float4*)&xr[c16 * 4 + i * 64];
        s  += v.x + v.y + v.z + v.w;
        sq += v.x * v.x + v.y * v.y + v.z * v.z + v.w * v.w;
    }
    psum[r][c16] = s; psq[r][c16] = sq;
    __syncthreads();
    if (t < 16) {
        float ss = 0.f, qq = 0.f;
        #pragma unroll
        for (int i = 0; i < 16; i++) { ss += psum[t][i]; qq += psq[t][i]; }
        float m = ss / (float)cD;
        mean_s[t] = m;
        rstd_s[t] = rsqrtf(qq / (float)cD - m * m + 1e-5f);
    }
    __syncthreads();
    int r2 = t & 15, cslot = t >> 4;
    const float* xr2 = x + ((size_t)R * 16 + r2) * cD;
    float m = mean_s[r2], rs = rstd_s[r2];
    for (int c = cslot; c < 96; c += 16) {
        float4 a0 = *(const float4*)&xr2[c * 8];
        float4 a1 = *(const float4*)&xr2[c * 8 + 4];
        float4 g0 = *(const float4*)&g[c * 8];
        float4 g1 = *(const float4*)&g[c * 8 + 4];
        float4 b0 = *(const float4*)&b[c * 8];
        float4 b1 = *(const float4*)&b[c * 8 + 4];
        unsigned short o[8];
        o[0] = f2bf((a0.x - m) * rs * g0.x + b0.x);
        o[1] = f2bf((a0.y - m) * rs * g0.y + b0.y);
        o[2] = f2bf((a0.z - m) * rs * g0.z + b0.z);
        o[3] = f2bf((a0.w - m) * rs * g0.w + b0.w);
        o[4] = f2bf((a1.x - m) * rs * g1.x + b1.x);
        o[5] = f2bf((a1.y - m) * rs * g1.y + b1.y);
        o[6] = f2bf((a1.z - m) * rs * g1.z + b1.z);
        o[7] = f2bf((a1.w - m) * rs * g1.w + b1.w);
        uint4 w;
        w.x = o[0] | ((unsigned)o[1] << 16); w.y = o[2] | ((unsigned)o[3] << 16);
        w.z = o[4] | ((unsigned)o[5] << 16); w.w = o[6] | ((unsigned)o[7] << 16);
        *(uint4*)&y[((size_t)R * 96 + c) * 128 + r2 * 8] = w;
    }
}

// ---------------------------------------------------------------------------
// MFMA GEMM, single-wave 64x64 blocks, BARRIER-FREE double-buffered pipeline:
// issue next K-step's global_load_lds into buf^1, s_waitcnt vmcnt(8) gates
// current buf, lgkmcnt(0) fences ds-reads before the buffer is reissued.
// modes: 0 row-major bf16 (ostride). 1: A-swizzled + GELU. 2: fp32 + res.
//        3: split: n < vsplit -> row-major bf16 (bias); n >= vsplit -> Vt
//           (biasB[n-vsplit]).  Vt: [b*12+h][d][tok] bf16.
// ---------------------------------------------------------------------------
__global__ __launch_bounds__(64)
void mfma_gemm(const unsigned short* __restrict__ A,
               const unsigned short* __restrict__ Bw,
               const float* __restrict__ bias, const float* __restrict__ biasB,
               const float* __restrict__ res,
               void* __restrict__ Cout, unsigned short* __restrict__ VtOut,
               int K, int N, int ostride, int vsplit, int mode) {
    __shared__ bf16x8 aF[2][4 * 64];
    __shared__ bf16x8 bF[2][4 * 64];
    int l = threadIdx.x;
    int m0 = blockIdx.x * 64, n0 = blockIdx.y * 64;
    int K8 = K >> 3;
    f32x4 acc[4][4];
    #pragma unroll
    for (int i = 0; i < 4; i++)
        #pragma unroll
        for (int j = 0; j < 4; j++) acc[i][j] = (f32x4){0.f, 0.f, 0.f, 0.f};

    const unsigned short* Ab = A  + (size_t)(m0 >> 4) * K8 * 128 + l * 8;
    const unsigned short* Bb = Bw + (size_t)(n0 >> 4) * K8 * 128 + l * 8;

    auto issue = [&](int buf, int k0) {
        int koff = (k0 >> 3) * 128;
        #pragma unroll
        for (int i = 0; i < 4; i++)
            gl_lds16(Ab + (size_t)i * K8 * 128 + koff, &aF[buf][i * 64]);
        #pragma unroll
        for (int i = 0; i < 4; i++)
            gl_lds16(Bb + (size_t)i * K8 * 128 + koff, &bF[buf][i * 64]);
    };

    issue(0, 0);
    int nsteps = K >> 5;
    for (int s = 0; s < nsteps; s++) {
        int cb = s & 1;
        if (s + 1 < nsteps) {
            issue(cb ^ 1, (s + 1) << 5);
            asm volatile("s_waitcnt vmcnt(8)" ::: "memory");
        } else {
            asm volatile("s_waitcnt vmcnt(0)" ::: "memory");
        }
        bf16x8 av[4], bv[4];
        #pragma unroll
        for (int i = 0; i < 4; i++) av[i] = aF[cb][i * 64 + l];
        #pragma unroll
        for (int j = 0; j < 4; j++) bv[j] = bF[cb][j * 64 + l];
        #pragma unroll
        for (int i = 0; i < 4; i++)
            #pragma unroll
            for (int j = 0; j < 4; j++)
                acc[i][j] = __builtin_amdgcn_mfma_f32_16x16x32_bf16(av[i], bv[j], acc[i][j], 0, 0, 0);
        // all ds_reads of buf cb retired before it is reissued next iteration
        asm volatile("s_waitcnt lgkmcnt(0)" ::: "memory");
    }

    int col = l & 15;
    int rb = (l >> 4) * 4;
    if (mode == 2) {
        float* out = (float*)Cout;
        #pragma unroll
        for (int j = 0; j < 4; j++) {
            int n = n0 + j * 16 + col;
            float bj = bias[n];
            #pragma unroll
            for (int i = 0; i < 4; i++)
                #pragma unroll
                for (int r = 0; r < 4; r++) {
                    int mm = m0 + i * 16 + rb + r;
                    out[(size_t)mm * ostride + n] = acc[i][j][r] + bj + res[(size_t)mm * ostride + n];
                }
        }
    } else if (mode == 1) {
        unsigned short* out = (unsigned short*)Cout;
        int N8 = N >> 3;
        #pragma unroll
        for (int j = 0; j < 4; j++) {
            int n = n0 + j * 16 + col;
            float bj = bias[n];
            #pragma unroll
            for (int i = 0; i < 4; i++)
                #pragma unroll
                for (int r = 0; r < 4; r++) {
                    int mm = m0 + i * 16 + rb + r;
                    float v = acc[i][j][r] + bj;
                    v = 0.5f * v * (1.0f + erff(v * 0.70710678118f));
                    size_t ad = ((size_t)(mm >> 4) * N8 + (n >> 3)) * 128 + (mm & 15) * 8 + (n & 7);
                    out[ad] = f2bf(v);
                }
        }
    } else {
        bool toVt = (mode == 3) && (n0 >= vsplit);
        if (!toVt) {
            unsigned short* out = (unsigned short*)Cout;
            #pragma unroll
            for (int j = 0; j < 4; j++) {
                int n = n0 + j * 16 + col;
                float bj = bias[n];
                #pragma unroll
                for (int i = 0; i < 4; i++)
                    #pragma unroll
                    for (int r = 0; r < 4; r++) {
                        int mm = m0 + i * 16 + rb + r;
                        out[(size_t)mm * ostride + n] = f2bf(acc[i][j][r] + bj);
                    }
            }
        } else {
            #pragma unroll
            for (int j = 0; j < 4; j++) {
                int n = n0 + j * 16 + col;
                int vc = n - vsplit;
                float bj = biasB[vc];
                int ph = vc >> 6, d = vc & 63;
                #pragma unroll
                for (int i = 0; i < 4; i++) {
                    int mm = m0 + i * 16 + rb;
                    int bbv = mm >> 10, tok = mm & 1023;
                    unsigned short q0 = f2bf(acc[i][j][0] + bj);
                    unsigned short q1 = f2bf(acc[i][j][1] + bj);
                    unsigned short q2 = f2bf(acc[i][j][2] + bj);
                    unsigned short q3 = f2bf(acc[i][j][3] + bj);
                    uint2 pk;
                    pk.x = q0 | ((unsigned)q1 << 16);
                    pk.y = q2 | ((unsigned)q3 << 16);
                    size_t ad = ((size_t)(bbv * 12 + ph) * 64 + d) * 1024 + tok;
                    *(uint2*)&VtOut[ad] = pk;
                }
            }
        }
    }
}

// ---------------------------------------------------------------------------
// MFMA flash attention, 4 independent waves/block, zero __syncthreads.
// ALL kf+vf loads issued at iteration top: vf latency covered by softmax,
// kf mostly L2-hit after first q-tile warms the head's K slice.
// ---------------------------------------------------------------------------
__global__ __launch_bounds__(256, 2)
void fattn_kernel(const unsigned short* __restrict__ Qp,
                  const unsigned short* __restrict__ Kp,
                  const unsigned short* __restrict__ Vt,
                  unsigned short* __restrict__ O,
                  int qk_stride, float scale) {
    __shared__ unsigned short Ps[4][16][72];

    int t = threadIdx.x;
    int w = t >> 6, l = t & 63;
    int la = l & 15, lb = l >> 4;
    int blk = blockIdx.x;
    int qt0 = (blk & 15) * 64 + w * 16;
    int bh = blk >> 4;
    int h = bh % cH, bb = bh / cH;

    const unsigned short* Qb = Qp + (size_t)(bb * cN) * qk_stride + h * cHD;
    const unsigned short* Kb = Kp + (size_t)(bb * cN) * qk_stride + h * cHD;
    const unsigned short* Vb = Vt + (size_t)(bb * cH + h) * (64 * 1024);

    bf16x8 av[2];
    #pragma unroll
    for (int s = 0; s < 2; s++)
        av[s] = *(const bf16x8*)(Qb + (size_t)(qt0 + la) * qk_stride + 32 * s + 8 * lb);

    float m_run[4], l_run[4];
    f32x4 acc_o[4];
    #pragma unroll
    for (int r = 0; r < 4; r++) { m_run[r] = -1e30f; l_run[r] = 0.f; }
    #pragma unroll
    for (int nt = 0; nt < 4; nt++) acc_o[nt] = (f32x4){0.f, 0.f, 0.f, 0.f};

    for (int kt0 = 0; kt0 < cN; kt0 += 64) {
        // ---- issue ALL loads for this tile up front
        bf16x8 kf[4][2];
        #pragma unroll
        for (int j = 0; j < 4; j++)
            #pragma unroll
            for (int s = 0; s < 2; s++)
                kf[j][s] = *(const bf16x8*)(Kb + (size_t)(kt0 + 16 * j + la) * qk_stride + 32 * s + 8 * lb);
        bf16x8 vf[4][2];
        #pragma unroll
        for (int nt = 0; nt < 4; nt++)
            #pragma unroll
            for (int s = 0; s < 2; s++)
                vf[nt][s] = *(const bf16x8*)(Vb + (size_t)(16 * nt + la) * 1024 + kt0 + 32 * s + 8 * lb);

        // ---- S = Q K^T
        f32x4 sj[4];
        #pragma unroll
        for (int j = 0; j < 4; j++) sj[j] = (f32x4){0.f, 0.f, 0.f, 0.f};
        #pragma unroll
        for (int j = 0; j < 4; j++)
            #pragma unroll
            for (int s = 0; s < 2; s++)
                sj[j] = __builtin_amdgcn_mfma_f32_16x16x32_bf16(av[s], kf[j][s], sj[j], 0, 0, 0);

        // ---- online softmax in registers
        float x[4][4];
        #pragma unroll
        for (int j = 0; j < 4; j++)
            #pragma unroll
            for (int r = 0; r < 4; r++) x[j][r] = sj[j][r] * scale;
        float mt[4];
        #pragma unroll
        for (int r = 0; r < 4; r++)
            mt[r] = fmaxf(fmaxf(x[0][r], x[1][r]), fmaxf(x[2][r], x[3][r]));
        #pragma unroll
        for (int off = 1; off <= 8; off <<= 1)
            #pragma unroll
            for (int r = 0; r < 4; r++)
                mt[r] = fmaxf(mt[r], __shfl_xor(mt[r], off, 64));
        float al[4];
        #pragma unroll
        for (int r = 0; r < 4; r++) {
            float mn = fmaxf(m_run[r], mt[r]);
            al[r] = __expf(m_run[r] - mn);
            m_run[r] = mn;
        }
        float p[4][4], ts[4] = {0.f, 0.f, 0.f, 0.f};
        #pragma unroll
        for (int j = 0; j < 4; j++)
            #pragma unroll
            for (int r = 0; r < 4; r++) {
                p[j][r] = __expf(x[j][r] - m_run[r]);
                ts[r] += p[j][r];
            }
        #pragma unroll
        for (int off = 1; off <= 8; off <<= 1)
            #pragma unroll
            for (int r = 0; r < 4; r++)
                ts[r] += __shfl_xor(ts[r], off, 64);
        #pragma unroll
        for (int r = 0; r < 4; r++) l_run[r] = l_run[r] * al[r] + ts[r];
        #pragma unroll
        for (int nt = 0; nt < 4; nt++)
            #pragma unroll
            for (int r = 0; r < 4; r++) acc_o[nt][r] *= al[r];

        // ---- P: C-layout regs -> wave-private LDS -> A-frags
        #pragma unroll
        for (int j = 0; j < 4; j++)
            #pragma unroll
            for (int r = 0; r < 4; r++)
                Ps[w][lb * 4 + r][16 * j + la] = f2bf(p[j][r]);
        asm volatile("s_waitcnt lgkmcnt(0)" ::: "memory");
        bf16x8 pf[2];
        #pragma unroll
        for (int s = 0; s < 2; s++)
            pf[s] = *(const bf16x8*)&Ps[w][la][32 * s + 8 * lb];

        // ---- O += P V
        #pragma unroll
        for (int nt = 0; nt < 4; nt++)
            #pragma unroll
            for (int s = 0; s < 2; s++)
                acc_o[nt] = __builtin_amdgcn_mfma_f32_16x16x32_bf16(pf[s], vf[nt][s], acc_o[nt], 0, 0, 0);
    }

    // ---- epilogue: O/l, A-swizzled store (K=768 layout)
    float inv[4];
    #pragma unroll
    for (int r = 0; r < 4; r++) inv[r] = 1.0f / l_run[r];
    size_t mhi = ((size_t)bb * cN + qt0) >> 4;
    #pragma unroll
    for (int nt = 0; nt < 4; nt++) {
        int k = h * cHD + 16 * nt + la;
        size_t base = (mhi * 96 + (k >> 3)) * 128 + (k & 7);
        #pragma unroll
        for (int r = 0; r < 4; r++) {
            unsigned short val = f2bf(acc_o[nt][r] * inv[r]);
            O[base + (lb * 4 + r) * 8] = val;
        }
    }
}

// ---------------------------------------------------------------------------
extern "C" void kernel_launch(void* const* d_in, const int* in_sizes, int n_in,
                              void* d_out, int out_size, void* d_ws, size_t ws_size,
                              hipStream_t stream) {
    const float* img_tok  = (const float*)d_in[0];
    const float* evt_tok  = (const float*)d_in[1];
    const float* ln_q1_g  = (const float*)d_in[2];
    const float* ln_q1_b  = (const float*)d_in[3];
    const float* ln_kv1_g = (const float*)d_in[4];
    const float* ln_kv1_b = (const float*)d_in[5];
    const float* ln_q2_g  = (const float*)d_in[6];
    const float* ln_q2_b  = (const float*)d_in[7];
    const float* ln_kv2_g = (const float*)d_in[8];
    const float* ln_kv2_b = (const float*)d_in[9];
    const float* ln_mi_g  = (const float*)d_in[10];
    const float* ln_mi_b  = (const float*)d_in[11];
    const float* ln_me_g  = (const float*)d_in[12];
    const float* ln_me_b  = (const float*)d_in[13];
    const float* si_qkv_w  = (const float*)d_in[14];
    const float* si_qkv_b  = (const float*)d_in[15];
    const float* si_proj_w = (const float*)d_in[16];
    const float* si_proj_b = (const float*)d_in[17];
    const float* se_qkv_w  = (const float*)d_in[18];
    const float* se_qkv_b  = (const float*)d_in[19];
    const float* se_proj_w = (const float*)d_in[20];
    const float* se_proj_b = (const float*)d_in[21];
    const float* xei_q_w = (const float*)d_in[22];
    const float* xei_q_b = (const float*)d_in[23];
    const float* xei_k_w = (const float*)d_in[24];
    const float* xei_k_b = (const float*)d_in[25];
    const float* xei_v_w = (const float*)d_in[26];
    const float* xei_v_b = (const float*)d_in[27];
    const float* xei_p_w = (const float*)d_in[28];
    const float* xei_p_b = (const float*)d_in[29];
    const float* xie_q_w = (const float*)d_in[30];
    const float* xie_q_b = (const float*)d_in[31];
    const float* xie_k_w = (const float*)d_in[32];
    const float* xie_k_b = (const float*)d_in[33];
    const float* xie_v_w = (const float*)d_in[34];
    const float* xie_v_b = (const float*)d_in[35];
    const float* xie_p_w = (const float*)d_in[36];
    const float* xie_p_b = (const float*)d_in[37];
    const float* mi_fc1_w = (const float*)d_in[38];
    const float* mi_fc1_b = (const float*)d_in[39];
    const float* mi_fc2_w = (const float*)d_in[40];
    const float* mi_fc2_b = (const float*)d_in[41];
    const float* me_fc1_w = (const float*)d_in[42];
    const float* me_fc1_b = (const float*)d_in[43];
    const float* me_fc2_w = (const float*)d_in[44];
    const float* me_fc2_b = (const float*)d_in[45];

    const size_t U = (size_t)cBN * cD;               // 3,145,728
    unsigned short* wsb = (unsigned short*)d_ws;
    unsigned short* Wz  = wsb;                       // 18,874,368 elems
    unsigned short* LNo = wsb + 18874368;            // U
    unsigned short* AO  = LNo + U;                   // U
    unsigned short* T1  = AO + U;                    // 3U (row stride 2304)
    unsigned short* Vt  = T1 + 3 * U;                // U  [48][64][1024]
    unsigned short* Hid = AO;                        // 4U alias (AO + T1)
    float* out_img = (float*)d_out;
    float* out_evt = out_img + U;

    // weight offsets (bf16 elems); 768x768 = 589824
    const size_t O_SI_QKV = 0,        O_SE_QKV = 1769472;
    const size_t O_SI_P   = 3538944,  O_SE_P   = 4128768;
    const size_t O_XEI_Q  = 4718592,  O_XEI_KV = 5308416, O_XEI_P = 6488064;
    const size_t O_XIE_Q  = 7077888,  O_XIE_KV = 7667712, O_XIE_P = 8847360;
    const size_t O_MI_F1  = 9437184,  O_MI_F2  = 11796480;
    const size_t O_ME_F1  = 14155776, O_ME_F2  = 16515072;

    auto wc = [&](const float* w, size_t off, int K, int N) {
        hipLaunchKernelGGL(wconv_kernel, dim3(K / 64, N / 64), dim3(256), 0, stream,
                           w, Wz + off, K, N);
    };
    auto ln = [&](const float* x_, const float* g_, const float* b_, unsigned short* y_) {
        hipLaunchKernelGGL(ln_kernel, dim3(cBN / 16), dim3(256), 0, stream, x_, g_, b_, y_);
    };
    auto gemm = [&](const unsigned short* A_, size_t woff, const float* b_, const float* bB_,
                    const float* r_, void* C_, int K_, int N_, int ostride_, int vsplit_, int mode_) {
        hipLaunchKernelGGL(mfma_gemm, dim3(cBN / 64, N_ / 64), dim3(64), 0, stream,
                           A_, Wz + woff, b_, bB_, r_, C_, Vt, K_, N_, ostride_, vsplit_, mode_);
    };
    auto attn = [&](const unsigned short* q_, const unsigned short* k_,
                    unsigned short* o_, float sc_) {
        hipLaunchKernelGGL(fattn_kernel, dim3(cB * cH * 16), dim3(256), 0, stream,
                           q_, k_, Vt, o_, 2304, sc_);
    };
    const float SC = 0.125f;

    // ---- weight conversion
    wc(si_qkv_w, O_SI_QKV, 768, 2304);  wc(se_qkv_w, O_SE_QKV, 768, 2304);
    wc(si_proj_w, O_SI_P, 768, 768);    wc(se_proj_w, O_SE_P, 768, 768);
    wc(xei_q_w, O_XEI_Q, 768, 768);
    wc(xei_k_w, O_XEI_KV, 768, 768);    wc(xei_v_w, O_XEI_KV + 589824, 768, 768);
    wc(xei_p_w, O_XEI_P, 768, 768);
    wc(xie_q_w, O_XIE_Q, 768, 768);
    wc(xie_k_w, O_XIE_KV, 768, 768);    wc(xie_v_w, O_XIE_KV + 589824, 768, 768);
    wc(xie_p_w, O_XIE_P, 768, 768);
    wc(mi_fc1_w, O_MI_F1, 768, 3072);   wc(mi_fc2_w, O_MI_F2, 3072, 768);
    wc(me_fc1_w, O_ME_F1, 768, 3072);   wc(me_fc2_w, O_ME_F2, 3072, 768);

    // ---- self-attn img
    ln(img_tok, ln_q1_g, ln_q1_b, LNo);
    gemm(LNo, O_SI_QKV, si_qkv_b, si_qkv_b + 1536, nullptr, T1, 768, 2304, 2304, 1536, 3);
    attn(T1, T1 + 768, AO, SC);
    gemm(AO, O_SI_P, si_proj_b, nullptr, img_tok, out_img, 768, 768, 768, 0, 2);

    // ---- self-attn evt
    ln(evt_tok, ln_kv1_g, ln_kv1_b, LNo);
    gemm(LNo, O_SE_QKV, se_qkv_b, se_qkv_b + 1536, nullptr, T1, 768, 2304, 2304, 1536, 3);
    attn(T1, T1 + 768, AO, SC);
    gemm(AO, O_SE_P, se_proj_b, nullptr, evt_tok, out_evt, 768, 768, 768, 0, 2);

    // ---- cross xei: q=ln_q2(i1), kv=ln_kv2(e1), negated
    ln(out_img, ln_q2_g, ln_q2_b, LNo);
    gemm(LNo, O_XEI_Q, xei_q_b, nullptr, nullptr, T1, 768, 768, 2304, 1 << 30, 0);
    ln(out_evt, ln_kv2_g, ln_kv2_b, LNo);
    gemm(LNo, O_XEI_KV, xei_k_b, xei_v_b, nullptr, T1 + 768, 768, 1536, 2304, 768, 3);
    attn(T1, T1 + 768, AO, -SC);

    // ---- xie inputs while i1/e1 intact (xei attn already consumed T1/Vt)
    ln(out_img, ln_kv2_g, ln_kv2_b, LNo);
    gemm(LNo, O_XIE_KV, xie_k_b, xie_v_b, nullptr, T1 + 768, 768, 1536, 2304, 768, 3);
    ln(out_evt, ln_q2_g, ln_q2_b, LNo);
    gemm(LNo, O_XIE_Q, xie_q_b, nullptr, nullptr, T1, 768, 768, 2304, 1 << 30, 0);

    gemm(AO, O_XEI_P, xei_p_b, nullptr, out_img, out_img, 768, 768, 768, 0, 2);   // i2
    attn(T1, T1 + 768, AO, -SC);
    gemm(AO, O_XIE_P, xie_p_b, nullptr, out_evt, out_evt, 768, 768, 768, 0, 2);   // e2

    // ---- MLP img
    ln(out_img, ln_mi_g, ln_mi_b, LNo);
    gemm(LNo, O_MI_F1, mi_fc1_b, nullptr, nullptr, Hid, 768, 3072, 3072, 0, 1);
    gemm(Hid, O_MI_F2, mi_fc2_b, nullptr, out_img, out_img, 3072, 768, 768, 0, 2);

    // ---- MLP evt
    ln(out_evt, ln_me_g, ln_me_b, LNo);
    gemm(LNo, O_ME_F1, me_fc1_b, nullptr, nullptr, Hid, 768, 3072, 3072, 0, 1);
    gemm(Hid, O_ME_F2, me_fc2_b, nullptr, out_evt, out_evt, 3072, 768, 768, 0, 2);
}